// Round 6
// baseline (6545.177 us; speedup 1.0000x reference)
//
#include <hip/hip_runtime.h>

// QCircuitBipartiteModel — round 6: edge-parallel LDS-atomic aggregation.
//  * r5 post-mortem: gate k_layer still latency-bound (Mfma 8%, VALU 26%, HBM 12%,
//    occ 21%) — per-lane serial CSR walk pays max-degree dependent-load chains.
//  * Gather rewritten: rows of a block are contiguous -> their CSR slab is contiguous.
//    Quarter-wave (16 lanes) per edge = one coalesced 256B row read; fp32 accumulate
//    into padded LDS [rows][132] via ds_add_f32. Coalesced index streams (csr + new
//    dmap dst-row array). No dependent chains.
//  * Gate side fused into k_layer<1> (LDS agg -> A-frags); qubit side standalone
//    k_agg_lds (64-row blocks) -> agg_q buffer (snapshot of pre-update gx needed).
//  * Per-row inv counts precomputed. ws ~206MB (< proven 220MB).

#define NGATE 500000
#define NQUB  100000
#define NEDGE 1000000
#define H     128
#define NL    4
#define NB    1024
#define EMB   16
#define GDIM  32
#define NTYPES 31

typedef unsigned int u32;
typedef unsigned short u16;
typedef __attribute__((ext_vector_type(8))) short short8;   // 8 bf16 = 4 VGPR
typedef __attribute__((ext_vector_type(4))) float f32x4;

__device__ __forceinline__ float silu_f(float x) { return x / (1.f + __expf(-x)); }
__device__ __forceinline__ u16 f2bf(float f) {
  u32 x = __float_as_uint(f);
  return (u16)((x + 0x7fffu + ((x >> 16) & 1u)) >> 16);  // RNE
}
__device__ __forceinline__ u32 pack2(float a, float b) {
  return (u32)f2bf(a) | ((u32)f2bf(b) << 16);
}
__device__ __forceinline__ float2 unpack2(u32 v) {
  return make_float2(__uint_as_float((v & 0xffffu) << 16), __uint_as_float((v >> 16) << 16));
}
__device__ __forceinline__ float bf16tof(u16 h) { return __uint_as_float(((u32)h) << 16); }

__global__ void k_sentinel(float* out) { out[0] = 10000.f; }

// ---------------- projections ----------------

__global__ __launch_bounds__(256) void k_gate_proj(
    const int* __restrict__ ty, const int* __restrict__ ar, const int* __restrict__ di,
    const float* __restrict__ ixn, const float* __restrict__ emb,
    const float* __restrict__ W, const float* __restrict__ bias, u32* __restrict__ gx) {
  __shared__ float sW[19 * H];
  __shared__ float se[NTYPES * EMB];
  __shared__ float sb[H];
  for (int i = threadIdx.x; i < 19 * H; i += 256) sW[i] = W[i];
  for (int i = threadIdx.x; i < NTYPES * EMB; i += 256) se[i] = emb[i];
  if (threadIdx.x < H) sb[threadIdx.x] = bias[threadIdx.x];
  __syncthreads();
  const float2* sW2 = (const float2*)sW;
  const float2* sb2 = (const float2*)sb;
  int lane = threadIdx.x & 63, wid = threadIdx.x >> 6;
  int gw = blockIdx.x * 4 + wid, nw = gridDim.x * 4;
  for (int r = gw; r < NGATE; r += nw) {
    int t = ty[r];
    float fa = (float)ar[r], fd = (float)di[r], fi = ixn[r];
    float2 b2v = sb2[lane];
    float al = b2v.x, ah = b2v.y;
#pragma unroll
    for (int k = 0; k < EMB; k++) {
      float e = se[t * EMB + k];
      float2 w = sW2[k * 64 + lane];
      al += e * w.x;
      ah += e * w.y;
    }
    float2 wa = sW2[16 * 64 + lane], wd = sW2[17 * 64 + lane], wi = sW2[18 * 64 + lane];
    al += fa * wa.x + fd * wd.x + fi * wi.x;
    ah += fa * wa.y + fd * wd.y + fi * wi.y;
    gx[(size_t)r * 64 + lane] = pack2(al, ah);
  }
}

__global__ __launch_bounds__(256) void k_qubit_proj(
    const float* __restrict__ deg, const float* __restrict__ W,
    const float* __restrict__ b, u32* __restrict__ qx) {
  int idx = blockIdx.x * 256 + threadIdx.x;
  if (idx >= NQUB * 64) return;
  int r = idx >> 6, l = idx & 63;
  float d = deg[r];
  qx[idx] = pack2(d * W[2 * l] + b[2 * l], d * W[2 * l + 1] + b[2 * l + 1]);
}

// ---------------- CSR build ----------------

__global__ __launch_bounds__(256) void k_count(
    const int* __restrict__ dq, const int* __restrict__ dg,
    int* __restrict__ cq, int* __restrict__ cg) {
  int e = blockIdx.x * 256 + threadIdx.x;
  if (e >= NEDGE) return;
  atomicAdd(&cq[dq[e]], 1);
  atomicAdd(&cg[dg[e]], 1);
}

__global__ __launch_bounds__(1024) void k_scan_chunk(
    const int* __restrict__ cnt, int n, int* __restrict__ out, int* __restrict__ bsum) {
  __shared__ int s[1024];
  int i = blockIdx.x * 1024 + threadIdx.x;
  int v = (i < n) ? cnt[i] : 0;
  s[threadIdx.x] = v;
  __syncthreads();
  for (int d = 1; d < 1024; d <<= 1) {
    int t = (threadIdx.x >= d) ? s[threadIdx.x - d] : 0;
    __syncthreads();
    s[threadIdx.x] += t;
    __syncthreads();
  }
  if (i < n) out[i] = s[threadIdx.x];
  if (threadIdx.x == 1023 && bsum) bsum[blockIdx.x] = s[1023];
}

__global__ __launch_bounds__(1024) void k_scan_add(
    int n, int* __restrict__ off, const int* __restrict__ bscan) {
  int i = blockIdx.x * 1024 + threadIdx.x;
  if (i < n && blockIdx.x > 0) off[i + 1] += bscan[blockIdx.x - 1];
  if (i == 0) off[0] = 0;
}

__global__ __launch_bounds__(256) void k_csr_fill(
    const int* __restrict__ sq, const int* __restrict__ dq,
    const int* __restrict__ sg, const int* __restrict__ dg,
    const int* __restrict__ offq, const int* __restrict__ offg,
    int* __restrict__ fq, int* __restrict__ fg,
    int* __restrict__ csrq, int* __restrict__ csrg,
    int* __restrict__ dmapq, int* __restrict__ dmapg) {
  int e = blockIdx.x * 256 + threadIdx.x;
  if (e >= NEDGE) return;
  int d1 = dq[e];
  int p1 = atomicAdd(&fq[d1], 1) + offq[d1];
  csrq[p1] = sq[e];
  dmapq[p1] = d1;
  int d2 = dg[e];
  int p2 = atomicAdd(&fg[d2], 1) + offg[d2];
  csrg[p2] = sg[e];
  dmapg[p2] = d2;
}

__global__ __launch_bounds__(256) void k_invcnt(
    const int* __restrict__ off, float* __restrict__ inv, int n) {
  int i = blockIdx.x * 256 + threadIdx.x;
  if (i < n) inv[i] = 1.f / fmaxf((float)(off[i + 1] - off[i]), 1.f);
}

// ---------------- weight prep: hi/lo bf16 B-frag tables ----------------

__global__ __launch_bounds__(256) void k_prep_w(
    const float* __restrict__ g2q_ll, const float* __restrict__ g2q_lr,
    const float* __restrict__ q2g_ll, const float* __restrict__ q2g_lr,
    u16* __restrict__ Whi, u16* __restrict__ Wlo) {
  int t = blockIdx.x * 256 + threadIdx.x;
  if (t >= 8 * 256 * 128) return;
  int o = t & 127, k = (t >> 7) & 255, mat = t >> 15;
  int l = mat >> 1, side = mat & 1;
  const float* Wll = side ? q2g_ll : g2q_ll;
  const float* Wlr = side ? q2g_lr : g2q_lr;
  float w = (k < 128) ? Wll[((size_t)l * 128 + k) * 128 + o]
                      : Wlr[((size_t)l * 128 + (k - 128)) * 128 + o];
  u16 hi = f2bf(w);
  float lof = w - bf16tof(hi);
  int ks = k >> 5, kr = k & 31, ot = o >> 4;
  int lane = ((kr >> 3) << 4) | (o & 15);
  int j = kr & 7;
  size_t pos = (((size_t)(mat * 8 + ks) * 8 + ot) * 64 + lane) * 8 + j;
  Whi[pos] = hi;
  Wlo[pos] = f2bf(lof);
}

__global__ __launch_bounds__(256) void k_prep_b(
    const float* __restrict__ g2q_llb, const float* __restrict__ g2q_lrb,
    const float* __restrict__ q2g_llb, const float* __restrict__ q2g_lrb,
    float* __restrict__ bcat) {
  int t = blockIdx.x * 256 + threadIdx.x;
  if (t >= 8 * 128) return;
  int c = t & 127, mat = t >> 7, l = mat >> 1, side = mat & 1;
  bcat[t] = side ? (q2g_llb[l * 128 + c] + q2g_lrb[l * 128 + c])
                 : (g2q_llb[l * 128 + c] + g2q_lrb[l * 128 + c]);
}

// ---------------- qubit agg: edge-parallel LDS gather, 64 rows/block ----------------

__global__ __launch_bounds__(256) void k_agg_lds(
    const u32* __restrict__ SRC, const int* __restrict__ off, const int* __restrict__ csr,
    const int* __restrict__ dmap, const float* __restrict__ inv,
    u32* __restrict__ OUT, int nrows) {
  __shared__ float sA[64 * 132];
  int tid = threadIdx.x;
  int R0 = blockIdx.x * 64;
  int R1 = min(R0 + 64, nrows);
  for (int i = tid; i < 64 * 132 / 4; i += 256)
    ((float4*)sA)[i] = make_float4(0.f, 0.f, 0.f, 0.f);
  __syncthreads();
  int e0 = off[R0], e1 = off[R1];
  int l16 = tid & 15;
  for (int e = e0 + (tid >> 4); e < e1; e += 16) {
    int s = csr[e];
    int rl = dmap[e] - R0;
    uint4 v = *(const uint4*)((const u16*)SRC + (size_t)s * 128 + l16 * 8);
    float* dp = sA + rl * 132 + l16 * 8;
    atomicAdd(dp + 0, __uint_as_float((v.x & 0xffffu) << 16));
    atomicAdd(dp + 1, __uint_as_float((v.x >> 16) << 16));
    atomicAdd(dp + 2, __uint_as_float((v.y & 0xffffu) << 16));
    atomicAdd(dp + 3, __uint_as_float((v.y >> 16) << 16));
    atomicAdd(dp + 4, __uint_as_float((v.z & 0xffffu) << 16));
    atomicAdd(dp + 5, __uint_as_float((v.z >> 16) << 16));
    atomicAdd(dp + 6, __uint_as_float((v.w & 0xffffu) << 16));
    atomicAdd(dp + 7, __uint_as_float((v.w >> 16) << 16));
  }
  __syncthreads();
  int nr = R1 - R0;
  for (int i = tid; i < nr * 64; i += 256) {
    int row = i >> 6, l = i & 63;
    size_t r = (size_t)R0 + row;
    float iv = inv[r];
    OUT[r * 64 + l] = pack2(sA[row * 132 + 2 * l] * iv, sA[row * 132 + 2 * l + 1] * iv);
  }
}

// ---------------- fused layer update (MFMA) ----------------
// X := LN(silu([AGG | X] @ Wcat + bcat)) * lng + lnb + X
// GATHER=1: block = 128 rows; edge-parallel LDS gather of SRCW rows (fp32 atomics),
//           then per-wave 32-row MFMA with A-frags read from LDS.
// GATHER=0: wave = 32 rows; AGG read from dense buffer AGG16 (pre-mean'ed).

template <int GATHER>
__global__ __launch_bounds__(256) void k_layer(
    const u16* __restrict__ AGG16, const u32* __restrict__ SRCW,
    const int* __restrict__ off, const int* __restrict__ csr,
    const int* __restrict__ dmap, const float* __restrict__ invv,
    u32* __restrict__ X, const u16* __restrict__ Whi, const u16* __restrict__ Wlo,
    const float* __restrict__ bcat, const float* __restrict__ lng,
    const float* __restrict__ lnb, int nrows) {
  __shared__ float sA[GATHER ? 128 * 132 : 4];
  int tid = threadIdx.x;
  int lane = tid & 63, wid = tid >> 6;
  int rlo = lane & 15, khi = lane >> 4;
  u16* X16 = (u16*)X;
  long r0;
  short8 ag[2][4];

  if constexpr (GATHER == 1) {
    int R0 = blockIdx.x * 128;
    int R1 = min(R0 + 128, nrows);
    for (int i = tid; i < 128 * 132 / 4; i += 256)
      ((float4*)sA)[i] = make_float4(0.f, 0.f, 0.f, 0.f);
    __syncthreads();
    int e0 = off[R0], e1 = off[R1];
    int l16 = tid & 15;
    for (int e = e0 + (tid >> 4); e < e1; e += 16) {
      int s = csr[e];
      int rl = dmap[e] - R0;
      uint4 v = *(const uint4*)((const u16*)SRCW + (size_t)s * 128 + l16 * 8);
      float* dp = sA + rl * 132 + l16 * 8;
      atomicAdd(dp + 0, __uint_as_float((v.x & 0xffffu) << 16));
      atomicAdd(dp + 1, __uint_as_float((v.x >> 16) << 16));
      atomicAdd(dp + 2, __uint_as_float((v.y & 0xffffu) << 16));
      atomicAdd(dp + 3, __uint_as_float((v.y >> 16) << 16));
      atomicAdd(dp + 4, __uint_as_float((v.z & 0xffffu) << 16));
      atomicAdd(dp + 5, __uint_as_float((v.z >> 16) << 16));
      atomicAdd(dp + 6, __uint_as_float((v.w & 0xffffu) << 16));
      atomicAdd(dp + 7, __uint_as_float((v.w >> 16) << 16));
    }
    __syncthreads();
    r0 = (long)R0 + wid * 32;
#pragma unroll
    for (int rs = 0; rs < 2; rs++) {
      int row_l = wid * 32 + rs * 16 + rlo;
      long rg = r0 + rs * 16 + rlo;
      if (rg > (long)nrows - 1) rg = nrows - 1;
      float iv = invv[rg];
      const float* sp = sA + row_l * 132;
#pragma unroll
      for (int ks = 0; ks < 4; ks++) {
        float4 f0 = *(const float4*)(sp + ks * 32 + khi * 8);
        float4 f1 = *(const float4*)(sp + ks * 32 + khi * 8 + 4);
        short8 af;
        af[0] = (short)f2bf(f0.x * iv);
        af[1] = (short)f2bf(f0.y * iv);
        af[2] = (short)f2bf(f0.z * iv);
        af[3] = (short)f2bf(f0.w * iv);
        af[4] = (short)f2bf(f1.x * iv);
        af[5] = (short)f2bf(f1.y * iv);
        af[6] = (short)f2bf(f1.z * iv);
        af[7] = (short)f2bf(f1.w * iv);
        ag[rs][ks] = af;
      }
    }
  } else {
    long wt = (long)blockIdx.x * 4 + wid;
    r0 = wt * 32;
    if (r0 >= nrows) return;
#pragma unroll
    for (int rs = 0; rs < 2; rs++) {
      long row = r0 + rs * 16 + rlo;
#pragma unroll
      for (int ks = 0; ks < 4; ks++)
        ag[rs][ks] = *(const short8*)(AGG16 + row * 128 + ks * 32 + khi * 8);
    }
  }

  // ---- MFMA main loop: K = 256 (ks 0..7), O = 128 (ot 0..7)
  f32x4 acc[2][8];
#pragma unroll
  for (int rs = 0; rs < 2; rs++)
#pragma unroll
    for (int ot = 0; ot < 8; ot++) acc[rs][ot] = (f32x4){0.f, 0.f, 0.f, 0.f};

#pragma unroll
  for (int ks = 0; ks < 8; ks++) {
    short8 a[2];
#pragma unroll
    for (int rs = 0; rs < 2; rs++) {
      if (ks < 4) {
        a[rs] = ag[rs][ks];
      } else {
        long row = r0 + rs * 16 + rlo;
        if (row > (long)nrows - 1) row = nrows - 1;
        a[rs] = *(const short8*)(X16 + row * 128 + (ks - 4) * 32 + khi * 8);
      }
    }
    const u16* bh_base = Whi + (size_t)ks * 4096 + (size_t)lane * 8;
    const u16* bl_base = Wlo + (size_t)ks * 4096 + (size_t)lane * 8;
#pragma unroll
    for (int ot = 0; ot < 8; ot++) {
      short8 bh = *(const short8*)(bh_base + ot * 512);
      short8 bl = *(const short8*)(bl_base + ot * 512);
#pragma unroll
      for (int rs = 0; rs < 2; rs++) {
        acc[rs][ot] = __builtin_amdgcn_mfma_f32_16x16x32_bf16(a[rs], bh, acc[rs][ot], 0, 0, 0);
        acc[rs][ot] = __builtin_amdgcn_mfma_f32_16x16x32_bf16(a[rs], bl, acc[rs][ot], 0, 0, 0);
      }
    }
  }

  // ---- epilogue: bias -> silu -> LN (16-lane-group reduce) -> residual -> store
  float bz[8], lg[8], lb[8];
#pragma unroll
  for (int ot = 0; ot < 8; ot++) {
    int c = ot * 16 + rlo;
    bz[ot] = bcat[c];
    lg[ot] = lng[c];
    lb[ot] = lnb[c];
  }
#pragma unroll
  for (int rs = 0; rs < 2; rs++) {
#pragma unroll
    for (int i = 0; i < 4; i++) {
      long row = r0 + rs * 16 + khi * 4 + i;
      float u[8], s1 = 0.f, s2 = 0.f;
#pragma unroll
      for (int ot = 0; ot < 8; ot++) {
        float z = acc[rs][ot][i] + bz[ot];
        float uu = silu_f(z);
        u[ot] = uu;
        s1 += uu;
        s2 += uu * uu;
      }
#pragma unroll
      for (int msk = 1; msk < 16; msk <<= 1) {
        s1 += __shfl_xor(s1, msk, 64);
        s2 += __shfl_xor(s2, msk, 64);
      }
      float mean = s1 * (1.f / 128.f);
      float var = s2 * (1.f / 128.f) - mean * mean;
      float rsq = rsqrtf(var + 1e-5f);
      if (row < nrows) {
#pragma unroll
        for (int ot = 0; ot < 8; ot++) {
          size_t idx = (size_t)row * 128 + ot * 16 + rlo;
          float xr = bf16tof(X16[idx]);
          float o = (u[ot] - mean) * rsq * lg[ot] + lb[ot] + xr;
          X16[idx] = f2bf(o);
        }
      }
    }
  }
}

// ---------------- batch stats / head ----------------

__global__ __launch_bounds__(256) void k_seg_counts(
    const int* __restrict__ batch, float* __restrict__ bcnt, int n) {
  int t = blockIdx.x * 256 + threadIdx.x;
  int r0 = t * 64;
  if (r0 >= n) return;
  int end = min(r0 + 64, n);
  int cur = batch[r0];
  float c = 0.f;
  for (int r = r0; r < end; r++) {
    int b = batch[r];
    if (b != cur) { atomicAdd(&bcnt[cur], c); cur = b; c = 0.f; }
    c += 1.f;
  }
  atomicAdd(&bcnt[cur], c);
}

__global__ __launch_bounds__(128) void k_bstats(
    const u32* __restrict__ X, const int* __restrict__ batch,
    float* __restrict__ bsum, float* __restrict__ bsq, int nrows) {
  __shared__ int sb[32];
  int r0 = blockIdx.x * 32;
  int c = threadIdx.x;
  if (c < 32) sb[c] = (r0 + c < nrows) ? batch[r0 + c] : -1;
  __syncthreads();
  float s = 0.f, q = 0.f;
  int cur = sb[0];
  const u16* Xh = (const u16*)X;
  for (int i = 0; i < 32; i++) {
    int r = r0 + i;
    if (r >= nrows) break;
    int b = sb[i];
    if (b != cur) {
      atomicAdd(&bsum[cur * H + c], s);
      atomicAdd(&bsq[cur * H + c], q);
      s = 0.f; q = 0.f; cur = b;
    }
    float v = bf16tof(Xh[(size_t)r * H + c]);
    s += v;
    q += v * v;
  }
  atomicAdd(&bsum[cur * H + c], s);
  atomicAdd(&bsq[cur * H + c], q);
}

__global__ __launch_bounds__(128) void k_head(
    const float* __restrict__ bsum_g, const float* __restrict__ bsq_g, const float* __restrict__ bcnt_g,
    const float* __restrict__ bsum_q, const float* __restrict__ bsq_q, const float* __restrict__ bcnt_q,
    const float* __restrict__ gf, const float* __restrict__ backend, const float* __restrict__ precision,
    const float* __restrict__ globW, const float* __restrict__ globb,
    const float* __restrict__ bbW, const float* __restrict__ bbb,
    const float* __restrict__ thrW, const float* __restrict__ thrb,
    const float* __restrict__ runW, const float* __restrict__ runb,
    float* __restrict__ out) {
  __shared__ float comb[5 * H + 2];
  __shared__ float feat[H];
  int b = blockIdx.x, c = threadIdx.x;
  float ig = 1.f / fmaxf(bcnt_g[b], 1.f);
  float iq = 1.f / fmaxf(bcnt_q[b], 1.f);
  float gm = bsum_g[b * H + c] * ig;
  float gs = sqrtf(fmaxf(bsq_g[b * H + c] * ig - gm * gm, 1e-6f));
  float qm = bsum_q[b * H + c] * iq;
  float qs = sqrtf(fmaxf(bsq_q[b * H + c] * iq - qm * qm, 1e-6f));
  float gl = globb[c];
#pragma unroll
  for (int j = 0; j < GDIM; j++) gl += gf[b * GDIM + j] * globW[j * H + c];
  gl = silu_f(gl);
  comb[c] = gm;
  comb[H + c] = gs;
  comb[2 * H + c] = qm;
  comb[3 * H + c] = qs;
  comb[4 * H + c] = gl;
  if (c == 0) {
    comb[5 * H] = backend[b];
    comb[5 * H + 1] = precision[b];
  }
  __syncthreads();
  float f = bbb[c];
  for (int k = 0; k < 5 * H + 2; k++) f += comb[k] * bbW[k * H + c];
  f = silu_f(f);
  feat[c] = f;
  __syncthreads();
  if (c < 10) {
    float o = thrb[c];
#pragma unroll
    for (int k = 0; k < H; k++) o += feat[k] * thrW[k * 10 + c];
    out[b * 10 + c] = o;
  }
  if (c == 64) {
    float o = runb[0];
    for (int k = 0; k < H; k++) o += feat[k] * runW[k];
    out[NB * 10 + b] = o;
  }
}

// ---------------- launch ----------------

extern "C" void kernel_launch(void* const* d_in, const int* in_sizes, int n_in,
                              void* d_out, int out_size, void* d_ws, size_t ws_size,
                              hipStream_t stream) {
  const int* gate_type = (const int*)d_in[0];
  const int* gate_arity = (const int*)d_in[1];
  const int* gate_dir = (const int*)d_in[2];
  const float* gate_ixn = (const float*)d_in[3];
  const float* qdeg = (const float*)d_in[4];
  const int* src_g2q = (const int*)d_in[5];
  const int* dst_g2q = (const int*)d_in[6];
  const int* src_q2g = (const int*)d_in[7];
  const int* dst_q2g = (const int*)d_in[8];
  const int* gate_batch = (const int*)d_in[9];
  const int* qubit_batch = (const int*)d_in[10];
  const float* gfeat = (const float*)d_in[11];
  const float* backend = (const float*)d_in[12];
  const float* precision = (const float*)d_in[13];
  const float* emb = (const float*)d_in[14];
  const float* gpW = (const float*)d_in[15];
  const float* gpb = (const float*)d_in[16];
  const float* qpW = (const float*)d_in[17];
  const float* qpb = (const float*)d_in[18];
  const float* g2q_ll_W = (const float*)d_in[19];
  const float* g2q_ll_b = (const float*)d_in[20];
  const float* g2q_lr_W = (const float*)d_in[21];
  const float* g2q_lr_b = (const float*)d_in[22];
  const float* q2g_ll_W = (const float*)d_in[23];
  const float* q2g_ll_b = (const float*)d_in[24];
  const float* q2g_lr_W = (const float*)d_in[25];
  const float* q2g_lr_b = (const float*)d_in[26];
  const float* gate_ln_g = (const float*)d_in[27];
  const float* gate_ln_b = (const float*)d_in[28];
  const float* qubit_ln_g = (const float*)d_in[29];
  const float* qubit_ln_b = (const float*)d_in[30];
  const float* globW = (const float*)d_in[31];
  const float* globb = (const float*)d_in[32];
  const float* bbW = (const float*)d_in[33];
  const float* bbb = (const float*)d_in[34];
  const float* thrW = (const float*)d_in[35];
  const float* thrb = (const float*)d_in[36];
  const float* runW = (const float*)d_in[37];
  const float* runb = (const float*)d_in[38];

  char* base = (char*)d_ws;
  u32* gx    = (u32*)base;                         // 128,000,000 B
  u32* qx    = gx + (size_t)NGATE * 64;            //  25,600,000 B
  u32* agg_q = qx + (size_t)NQUB * 64;             //  25,600,000 B
  u16* Whi   = (u16*)(agg_q + (size_t)NQUB * 64);  //     524,288 B
  u16* Wlo   = Whi + 8 * 32768;                    //     524,288 B
  float* bcat = (float*)(Wlo + 8 * 32768);         //       4,096 B
  int* offq = (int*)(bcat + 8 * 128);              // NQUB+1
  int* offg = offq + (NQUB + 1);                   // NGATE+1
  int* csrq = offg + (NGATE + 1);                  // NEDGE
  int* csrg = csrq + NEDGE;                        // NEDGE
  int* dmapq = csrg + NEDGE;                       // NEDGE
  int* dmapg = dmapq + NEDGE;                      // NEDGE
  int* cntq = dmapg + NEDGE;                       // NQUB
  int* cntg = cntq + NQUB;                         // NGATE
  float* invq = (float*)(cntg + NGATE);            // NQUB
  float* invg = invq + NQUB;                       // NGATE
  int* bsumA = (int*)(invg + NGATE);               // 512
  int* bsumB = bsumA + 512;                        // 512
  float* bsum_g = (float*)(bsumB + 512);
  float* bsq_g  = bsum_g + NB * H;
  float* bsum_q = bsq_g + NB * H;
  float* bsq_q  = bsum_q + NB * H;
  float* bcnt_g = bsq_q + NB * H;                  // NB
  float* bcnt_q = bcnt_g + NB;                     // NB
  size_t need = (size_t)((char*)(bcnt_q + NB) - base);
  if (ws_size < need) {
    k_sentinel<<<1, 1, 0, stream>>>((float*)d_out);
    return;
  }

  // ---- weight prep (layer-invariant) ----
  k_prep_w<<<(8 * 256 * 128 + 255) / 256, 256, 0, stream>>>(
      g2q_ll_W, g2q_lr_W, q2g_ll_W, q2g_lr_W, Whi, Wlo);
  k_prep_b<<<4, 256, 0, stream>>>(g2q_ll_b, g2q_lr_b, q2g_ll_b, q2g_lr_b, bcat);

  // ---- CSR build (layer-invariant) ----
  hipMemsetAsync(cntq, 0, (size_t)(NQUB + NGATE) * sizeof(int), stream);
  k_count<<<(NEDGE + 255) / 256, 256, 0, stream>>>(dst_g2q, dst_q2g, cntq, cntg);
  const int nbq = (NQUB + 1023) / 1024, nbg = (NGATE + 1023) / 1024;
  k_scan_chunk<<<nbq, 1024, 0, stream>>>(cntq, NQUB, offq + 1, bsumA);
  k_scan_chunk<<<1, 1024, 0, stream>>>(bsumA, nbq, bsumB, nullptr);
  k_scan_add<<<nbq, 1024, 0, stream>>>(NQUB, offq, bsumB);
  k_scan_chunk<<<nbg, 1024, 0, stream>>>(cntg, NGATE, offg + 1, bsumA);
  k_scan_chunk<<<1, 1024, 0, stream>>>(bsumA, nbg, bsumB, nullptr);
  k_scan_add<<<nbg, 1024, 0, stream>>>(NGATE, offg, bsumB);
  hipMemsetAsync(cntq, 0, (size_t)(NQUB + NGATE) * sizeof(int), stream);
  k_csr_fill<<<(NEDGE + 255) / 256, 256, 0, stream>>>(
      src_g2q, dst_g2q, src_q2g, dst_q2g, offq, offg, cntq, cntg,
      csrq, csrg, dmapq, dmapg);
  k_invcnt<<<(NQUB + 255) / 256, 256, 0, stream>>>(offq, invq, NQUB);
  k_invcnt<<<(NGATE + 255) / 256, 256, 0, stream>>>(offg, invg, NGATE);

  // ---- batch seg counts + stats init ----
  size_t stats_floats = 4ULL * NB * H + 2ULL * NB;
  hipMemsetAsync(bsum_g, 0, stats_floats * sizeof(float), stream);
  k_seg_counts<<<(NGATE / 64 + 256) / 256, 256, 0, stream>>>(gate_batch, bcnt_g, NGATE);
  k_seg_counts<<<(NQUB / 64 + 256) / 256, 256, 0, stream>>>(qubit_batch, bcnt_q, NQUB);

  // ---- projections ----
  k_gate_proj<<<1024, 256, 0, stream>>>(gate_type, gate_arity, gate_dir, gate_ixn,
                                        emb, gpW, gpb, gx);
  k_qubit_proj<<<(NQUB * 64 + 255) / 256, 256, 0, stream>>>(qdeg, qpW, qpb, qx);

  // ---- layers ----
  const int blocks_g = (NGATE + 127) / 128;     // 3907
  const int blocks_q = ((NQUB / 32) + 3) / 4;   // 782
  const int blocks_a = (NQUB + 63) / 64;        // 1563
  for (int l = 0; l < NL; l++) {
    // agg_q = seg-mean(old gx)  [before gate-side overwrites gx]
    k_agg_lds<<<blocks_a, 256, 0, stream>>>(gx, offq, csrq, dmapq, invq, agg_q, NQUB);
    // gate side: gx = LN(silu([gather-mean(old qx) | gx] @ Wcat + b)) + gx
    k_layer<1><<<blocks_g, 256, 0, stream>>>(
        nullptr, qx, offg, csrg, dmapg, invg, gx,
        Whi + (size_t)(l * 2 + 1) * 32768, Wlo + (size_t)(l * 2 + 1) * 32768,
        bcat + (l * 2 + 1) * 128, gate_ln_g + (size_t)l * H, gate_ln_b + (size_t)l * H, NGATE);
    // qubit side: qx = LN(silu([agg_q | qx] @ Wcat + b)) + qx
    k_layer<0><<<blocks_q, 256, 0, stream>>>(
        (const u16*)agg_q, nullptr, nullptr, nullptr, nullptr, nullptr, qx,
        Whi + (size_t)(l * 2) * 32768, Wlo + (size_t)(l * 2) * 32768,
        bcat + (l * 2) * 128, qubit_ln_g + (size_t)l * H, qubit_ln_b + (size_t)l * H, NQUB);
  }

  // ---- readout ----
  k_bstats<<<NGATE / 32, 128, 0, stream>>>(gx, gate_batch, bsum_g, bsq_g, NGATE);
  k_bstats<<<NQUB / 32, 128, 0, stream>>>(qx, qubit_batch, bsum_q, bsq_q, NQUB);
  k_head<<<NB, 128, 0, stream>>>(bsum_g, bsq_g, bcnt_g, bsum_q, bsq_q, bcnt_q,
                                 gfeat, backend, precision, globW, globb,
                                 bbW, bbb, thrW, thrb, runW, runb, (float*)d_out);
}

// Round 7
// 2020.160 us; speedup vs baseline: 3.2399x; 3.2399x over previous
//
#include <hip/hip_runtime.h>

// QCircuitBipartiteModel — round 7: revert r6's LDS-atomic gather (1M bank conflicts,
// 2.4x regression). Base = r5 (2255us) +:
//  * k_gather_rows: 4-way clamp-unrolled edge walk (deg<=4 -> one vmcnt round).
//  * k_layer<1> fused gather: 2-way unrolled (8 16B loads in flight).
//  * Split path when ws_size permits (+128MB agg_g bf16): gate agg via standalone
//    high-occupancy k_gather_rows (deg~2 -> ~1 latency round), gate update via pure
//    streaming k_layer<0>. Guarded by ws_size -> deterministic; fused fallback kept.

#define NGATE 500000
#define NQUB  100000
#define NEDGE 1000000
#define H     128
#define NL    4
#define NB    1024
#define EMB   16
#define GDIM  32
#define NTYPES 31

typedef unsigned int u32;
typedef unsigned short u16;
typedef __attribute__((ext_vector_type(8))) short short8;   // 8 bf16 = 4 VGPR
typedef __attribute__((ext_vector_type(4))) float f32x4;

__device__ __forceinline__ float silu_f(float x) { return x / (1.f + __expf(-x)); }
__device__ __forceinline__ u16 f2bf(float f) {
  u32 x = __float_as_uint(f);
  return (u16)((x + 0x7fffu + ((x >> 16) & 1u)) >> 16);  // RNE
}
__device__ __forceinline__ u32 pack2(float a, float b) {
  return (u32)f2bf(a) | ((u32)f2bf(b) << 16);
}
__device__ __forceinline__ float2 unpack2(u32 v) {
  return make_float2(__uint_as_float((v & 0xffffu) << 16), __uint_as_float((v >> 16) << 16));
}
__device__ __forceinline__ float bf16tof(u16 h) { return __uint_as_float(((u32)h) << 16); }

__global__ void k_sentinel(float* out) { out[0] = 10000.f; }

// ---------------- projections ----------------

__global__ __launch_bounds__(256) void k_gate_proj(
    const int* __restrict__ ty, const int* __restrict__ ar, const int* __restrict__ di,
    const float* __restrict__ ixn, const float* __restrict__ emb,
    const float* __restrict__ W, const float* __restrict__ bias, u32* __restrict__ gx) {
  __shared__ float sW[19 * H];
  __shared__ float se[NTYPES * EMB];
  __shared__ float sb[H];
  for (int i = threadIdx.x; i < 19 * H; i += 256) sW[i] = W[i];
  for (int i = threadIdx.x; i < NTYPES * EMB; i += 256) se[i] = emb[i];
  if (threadIdx.x < H) sb[threadIdx.x] = bias[threadIdx.x];
  __syncthreads();
  const float2* sW2 = (const float2*)sW;
  const float2* sb2 = (const float2*)sb;
  int lane = threadIdx.x & 63, wid = threadIdx.x >> 6;
  int gw = blockIdx.x * 4 + wid, nw = gridDim.x * 4;
  for (int r = gw; r < NGATE; r += nw) {
    int t = ty[r];
    float fa = (float)ar[r], fd = (float)di[r], fi = ixn[r];
    float2 b2v = sb2[lane];
    float al = b2v.x, ah = b2v.y;
#pragma unroll
    for (int k = 0; k < EMB; k++) {
      float e = se[t * EMB + k];
      float2 w = sW2[k * 64 + lane];
      al += e * w.x;
      ah += e * w.y;
    }
    float2 wa = sW2[16 * 64 + lane], wd = sW2[17 * 64 + lane], wi = sW2[18 * 64 + lane];
    al += fa * wa.x + fd * wd.x + fi * wi.x;
    ah += fa * wa.y + fd * wd.y + fi * wi.y;
    gx[(size_t)r * 64 + lane] = pack2(al, ah);
  }
}

__global__ __launch_bounds__(256) void k_qubit_proj(
    const float* __restrict__ deg, const float* __restrict__ W,
    const float* __restrict__ b, u32* __restrict__ qx) {
  int idx = blockIdx.x * 256 + threadIdx.x;
  if (idx >= NQUB * 64) return;
  int r = idx >> 6, l = idx & 63;
  float d = deg[r];
  qx[idx] = pack2(d * W[2 * l] + b[2 * l], d * W[2 * l + 1] + b[2 * l + 1]);
}

// ---------------- CSR build ----------------

__global__ __launch_bounds__(256) void k_count(
    const int* __restrict__ dq, const int* __restrict__ dg,
    int* __restrict__ cq, int* __restrict__ cg) {
  int e = blockIdx.x * 256 + threadIdx.x;
  if (e >= NEDGE) return;
  atomicAdd(&cq[dq[e]], 1);
  atomicAdd(&cg[dg[e]], 1);
}

__global__ __launch_bounds__(1024) void k_scan_chunk(
    const int* __restrict__ cnt, int n, int* __restrict__ out, int* __restrict__ bsum) {
  __shared__ int s[1024];
  int i = blockIdx.x * 1024 + threadIdx.x;
  int v = (i < n) ? cnt[i] : 0;
  s[threadIdx.x] = v;
  __syncthreads();
  for (int d = 1; d < 1024; d <<= 1) {
    int t = (threadIdx.x >= d) ? s[threadIdx.x - d] : 0;
    __syncthreads();
    s[threadIdx.x] += t;
    __syncthreads();
  }
  if (i < n) out[i] = s[threadIdx.x];
  if (threadIdx.x == 1023 && bsum) bsum[blockIdx.x] = s[1023];
}

__global__ __launch_bounds__(1024) void k_scan_add(
    int n, int* __restrict__ off, const int* __restrict__ bscan) {
  int i = blockIdx.x * 1024 + threadIdx.x;
  if (i < n && blockIdx.x > 0) off[i + 1] += bscan[blockIdx.x - 1];
  if (i == 0) off[0] = 0;
}

__global__ __launch_bounds__(256) void k_csr_fill(
    const int* __restrict__ sq, const int* __restrict__ dq,
    const int* __restrict__ sg, const int* __restrict__ dg,
    const int* __restrict__ offq, const int* __restrict__ offg,
    int* __restrict__ fq, int* __restrict__ fg,
    int* __restrict__ csrq, int* __restrict__ csrg) {
  int e = blockIdx.x * 256 + threadIdx.x;
  if (e >= NEDGE) return;
  int d1 = dq[e];
  int p1 = atomicAdd(&fq[d1], 1);
  csrq[offq[d1] + p1] = sq[e];
  int d2 = dg[e];
  int p2 = atomicAdd(&fg[d2], 1);
  csrg[offg[d2] + p2] = sg[e];
}

// ---------------- weight prep: hi/lo bf16 B-frag tables ----------------

__global__ __launch_bounds__(256) void k_prep_w(
    const float* __restrict__ g2q_ll, const float* __restrict__ g2q_lr,
    const float* __restrict__ q2g_ll, const float* __restrict__ q2g_lr,
    u16* __restrict__ Whi, u16* __restrict__ Wlo) {
  int t = blockIdx.x * 256 + threadIdx.x;
  if (t >= 8 * 256 * 128) return;
  int o = t & 127, k = (t >> 7) & 255, mat = t >> 15;
  int l = mat >> 1, side = mat & 1;
  const float* Wll = side ? q2g_ll : g2q_ll;
  const float* Wlr = side ? q2g_lr : g2q_lr;
  float w = (k < 128) ? Wll[((size_t)l * 128 + k) * 128 + o]
                      : Wlr[((size_t)l * 128 + (k - 128)) * 128 + o];
  u16 hi = f2bf(w);
  float lof = w - bf16tof(hi);
  int ks = k >> 5, kr = k & 31, ot = o >> 4;
  int lane = ((kr >> 3) << 4) | (o & 15);
  int j = kr & 7;
  size_t pos = (((size_t)(mat * 8 + ks) * 8 + ot) * 64 + lane) * 8 + j;
  Whi[pos] = hi;
  Wlo[pos] = f2bf(lof);
}

__global__ __launch_bounds__(256) void k_prep_b(
    const float* __restrict__ g2q_llb, const float* __restrict__ g2q_lrb,
    const float* __restrict__ q2g_llb, const float* __restrict__ q2g_lrb,
    float* __restrict__ bcat) {
  int t = blockIdx.x * 256 + threadIdx.x;
  if (t >= 8 * 128) return;
  int c = t & 127, mat = t >> 7, l = mat >> 1, side = mat & 1;
  bcat[t] = side ? (q2g_llb[l * 128 + c] + q2g_lrb[l * 128 + c])
                 : (g2q_llb[l * 128 + c] + g2q_lrb[l * 128 + c]);
}

// ---------------- seg-mean gather: wave per row, 4-way unrolled edge walk ----------------

__global__ __launch_bounds__(256) void k_gather_rows(
    const u32* __restrict__ SRC, const int* __restrict__ off, const int* __restrict__ csr,
    u32* __restrict__ OUT, int n) {
  int lane = threadIdx.x & 63, wid = threadIdx.x >> 6;
  int w = blockIdx.x * 4 + wid, nw = gridDim.x * 4;
  for (int r = w; r < n; r += nw) {
    int b = off[r], e = off[r + 1];
    float sl = 0.f, sh = 0.f;
    for (int t = b; t < e; t += 4) {
      int t1 = min(t + 1, e - 1), t2 = min(t + 2, e - 1), t3 = min(t + 3, e - 1);
      float w1 = (t + 1 < e) ? 1.f : 0.f;
      float w2 = (t + 2 < e) ? 1.f : 0.f;
      float w3 = (t + 3 < e) ? 1.f : 0.f;
      u32 v0 = SRC[(size_t)csr[t] * 64 + lane];
      u32 v1 = SRC[(size_t)csr[t1] * 64 + lane];
      u32 v2 = SRC[(size_t)csr[t2] * 64 + lane];
      u32 v3 = SRC[(size_t)csr[t3] * 64 + lane];
      float2 f0 = unpack2(v0), f1 = unpack2(v1), f2 = unpack2(v2), f3 = unpack2(v3);
      sl += f0.x + w1 * f1.x + w2 * f2.x + w3 * f3.x;
      sh += f0.y + w1 * f1.y + w2 * f2.y + w3 * f3.y;
    }
    float inv = 1.f / fmaxf((float)(e - b), 1.f);
    OUT[(size_t)r * 64 + lane] = pack2(sl * inv, sh * inv);
  }
}

// ---------------- fused layer update (MFMA), 32 rows/wave ----------------
// X := LN(silu([AGG | X] @ Wcat + bcat)) * lng + lnb + X
// GATHER=0: AGG from dense buffer AGG16 (pre-mean'ed).
// GATHER=1: AGG = CSR gather-mean of SRC16 rows, hoisted pre-pass, 2-way unrolled.
// nrows must be a multiple of 32.

template <int GATHER>
__global__ __launch_bounds__(256) void k_layer(
    const u16* __restrict__ AGG16, const u16* __restrict__ SRC16,
    const int* __restrict__ off, const int* __restrict__ csr,
    u32* __restrict__ X, const u16* __restrict__ Whi, const u16* __restrict__ Wlo,
    const float* __restrict__ bcat, const float* __restrict__ lng,
    const float* __restrict__ lnb, int nrows) {
  int lane = threadIdx.x & 63, wid = threadIdx.x >> 6;
  long wt = (long)blockIdx.x * 4 + wid;
  long r0 = wt * 32;
  if (r0 >= nrows) return;
  int rlo = lane & 15, khi = lane >> 4;
  u16* X16 = (u16*)X;

  // ---- hoisted A-frags for the aggregate (K-lo) half: ag[rs][ks]
  short8 ag[2][4];
#pragma unroll
  for (int rs = 0; rs < 2; rs++) {
    long row = r0 + rs * 16 + rlo;
    if (GATHER == 0) {
#pragma unroll
      for (int ks = 0; ks < 4; ks++)
        ag[rs][ks] = *(const short8*)(AGG16 + row * 128 + ks * 32 + khi * 8);
    } else {
      int bgn = off[row], end = off[row + 1];
      float m[4][8];
#pragma unroll
      for (int ks = 0; ks < 4; ks++)
#pragma unroll
        for (int j = 0; j < 8; j++) m[ks][j] = 0.f;
      for (int t = bgn; t < end; t += 2) {
        int t1 = min(t + 1, end - 1);
        float w1 = (t + 1 < end) ? 1.f : 0.f;
        const u16* p0 = SRC16 + (size_t)csr[t] * 128 + khi * 8;
        const u16* p1 = SRC16 + (size_t)csr[t1] * 128 + khi * 8;
        uint4 a0 = *(const uint4*)(p0);
        uint4 a1 = *(const uint4*)(p0 + 32);
        uint4 a2 = *(const uint4*)(p0 + 64);
        uint4 a3 = *(const uint4*)(p0 + 96);
        uint4 b0 = *(const uint4*)(p1);
        uint4 b1 = *(const uint4*)(p1 + 32);
        uint4 b2 = *(const uint4*)(p1 + 64);
        uint4 b3 = *(const uint4*)(p1 + 96);
        uint4 va[4] = {a0, a1, a2, a3};
        uint4 vb[4] = {b0, b1, b2, b3};
#pragma unroll
        for (int ks = 0; ks < 4; ks++) {
          m[ks][0] += __uint_as_float((va[ks].x & 0xffffu) << 16) + w1 * __uint_as_float((vb[ks].x & 0xffffu) << 16);
          m[ks][1] += __uint_as_float((va[ks].x >> 16) << 16) + w1 * __uint_as_float((vb[ks].x >> 16) << 16);
          m[ks][2] += __uint_as_float((va[ks].y & 0xffffu) << 16) + w1 * __uint_as_float((vb[ks].y & 0xffffu) << 16);
          m[ks][3] += __uint_as_float((va[ks].y >> 16) << 16) + w1 * __uint_as_float((vb[ks].y >> 16) << 16);
          m[ks][4] += __uint_as_float((va[ks].z & 0xffffu) << 16) + w1 * __uint_as_float((vb[ks].z & 0xffffu) << 16);
          m[ks][5] += __uint_as_float((va[ks].z >> 16) << 16) + w1 * __uint_as_float((vb[ks].z >> 16) << 16);
          m[ks][6] += __uint_as_float((va[ks].w & 0xffffu) << 16) + w1 * __uint_as_float((vb[ks].w & 0xffffu) << 16);
          m[ks][7] += __uint_as_float((va[ks].w >> 16) << 16) + w1 * __uint_as_float((vb[ks].w >> 16) << 16);
        }
      }
      float inv = 1.f / fmaxf((float)(end - bgn), 1.f);
#pragma unroll
      for (int ks = 0; ks < 4; ks++) {
        short8 af;
#pragma unroll
        for (int j = 0; j < 8; j++) af[j] = (short)f2bf(m[ks][j] * inv);
        ag[rs][ks] = af;
      }
    }
  }

  // ---- MFMA main loop: K = 256 (ks 0..7), O = 128 (ot 0..7)
  f32x4 acc[2][8];
#pragma unroll
  for (int rs = 0; rs < 2; rs++)
#pragma unroll
    for (int ot = 0; ot < 8; ot++) acc[rs][ot] = (f32x4){0.f, 0.f, 0.f, 0.f};

#pragma unroll
  for (int ks = 0; ks < 8; ks++) {
    short8 a[2];
#pragma unroll
    for (int rs = 0; rs < 2; rs++) {
      if (ks < 4)
        a[rs] = ag[rs][ks];
      else
        a[rs] = *(const short8*)(X16 + (r0 + rs * 16 + rlo) * 128 + (ks - 4) * 32 + khi * 8);
    }
    const u16* bh_base = Whi + (size_t)ks * 4096 + (size_t)lane * 8;
    const u16* bl_base = Wlo + (size_t)ks * 4096 + (size_t)lane * 8;
#pragma unroll
    for (int ot = 0; ot < 8; ot++) {
      short8 bh = *(const short8*)(bh_base + ot * 512);
      short8 bl = *(const short8*)(bl_base + ot * 512);
#pragma unroll
      for (int rs = 0; rs < 2; rs++) {
        acc[rs][ot] = __builtin_amdgcn_mfma_f32_16x16x32_bf16(a[rs], bh, acc[rs][ot], 0, 0, 0);
        acc[rs][ot] = __builtin_amdgcn_mfma_f32_16x16x32_bf16(a[rs], bl, acc[rs][ot], 0, 0, 0);
      }
    }
  }

  // ---- epilogue: bias -> silu -> LN (16-lane-group reduce) -> residual -> store
  float bz[8], lg[8], lb[8];
#pragma unroll
  for (int ot = 0; ot < 8; ot++) {
    int c = ot * 16 + rlo;
    bz[ot] = bcat[c];
    lg[ot] = lng[c];
    lb[ot] = lnb[c];
  }
#pragma unroll
  for (int rs = 0; rs < 2; rs++) {
#pragma unroll
    for (int i = 0; i < 4; i++) {
      long row = r0 + rs * 16 + khi * 4 + i;
      float u[8], s1 = 0.f, s2 = 0.f;
#pragma unroll
      for (int ot = 0; ot < 8; ot++) {
        float z = acc[rs][ot][i] + bz[ot];
        float uu = silu_f(z);
        u[ot] = uu;
        s1 += uu;
        s2 += uu * uu;
      }
#pragma unroll
      for (int msk = 1; msk < 16; msk <<= 1) {
        s1 += __shfl_xor(s1, msk, 64);
        s2 += __shfl_xor(s2, msk, 64);
      }
      float mean = s1 * (1.f / 128.f);
      float var = s2 * (1.f / 128.f) - mean * mean;
      float rsq = rsqrtf(var + 1e-5f);
#pragma unroll
      for (int ot = 0; ot < 8; ot++) {
        size_t idx = (size_t)row * 128 + ot * 16 + rlo;
        float xr = bf16tof(X16[idx]);
        float o = (u[ot] - mean) * rsq * lg[ot] + lb[ot] + xr;
        X16[idx] = f2bf(o);
      }
    }
  }
}

// ---------------- batch stats / head ----------------

__global__ __launch_bounds__(256) void k_seg_counts(
    const int* __restrict__ batch, float* __restrict__ bcnt, int n) {
  int t = blockIdx.x * 256 + threadIdx.x;
  int r0 = t * 64;
  if (r0 >= n) return;
  int end = min(r0 + 64, n);
  int cur = batch[r0];
  float c = 0.f;
  for (int r = r0; r < end; r++) {
    int b = batch[r];
    if (b != cur) { atomicAdd(&bcnt[cur], c); cur = b; c = 0.f; }
    c += 1.f;
  }
  atomicAdd(&bcnt[cur], c);
}

__global__ __launch_bounds__(128) void k_bstats(
    const u32* __restrict__ X, const int* __restrict__ batch,
    float* __restrict__ bsum, float* __restrict__ bsq, int nrows) {
  __shared__ int sb[32];
  int r0 = blockIdx.x * 32;
  int c = threadIdx.x;
  if (c < 32) sb[c] = (r0 + c < nrows) ? batch[r0 + c] : -1;
  __syncthreads();
  float s = 0.f, q = 0.f;
  int cur = sb[0];
  const u16* Xh = (const u16*)X;
  for (int i = 0; i < 32; i++) {
    int r = r0 + i;
    if (r >= nrows) break;
    int b = sb[i];
    if (b != cur) {
      atomicAdd(&bsum[cur * H + c], s);
      atomicAdd(&bsq[cur * H + c], q);
      s = 0.f; q = 0.f; cur = b;
    }
    float v = bf16tof(Xh[(size_t)r * H + c]);
    s += v;
    q += v * v;
  }
  atomicAdd(&bsum[cur * H + c], s);
  atomicAdd(&bsq[cur * H + c], q);
}

__global__ __launch_bounds__(128) void k_head(
    const float* __restrict__ bsum_g, const float* __restrict__ bsq_g, const float* __restrict__ bcnt_g,
    const float* __restrict__ bsum_q, const float* __restrict__ bsq_q, const float* __restrict__ bcnt_q,
    const float* __restrict__ gf, const float* __restrict__ backend, const float* __restrict__ precision,
    const float* __restrict__ globW, const float* __restrict__ globb,
    const float* __restrict__ bbW, const float* __restrict__ bbb,
    const float* __restrict__ thrW, const float* __restrict__ thrb,
    const float* __restrict__ runW, const float* __restrict__ runb,
    float* __restrict__ out) {
  __shared__ float comb[5 * H + 2];
  __shared__ float feat[H];
  int b = blockIdx.x, c = threadIdx.x;
  float ig = 1.f / fmaxf(bcnt_g[b], 1.f);
  float iq = 1.f / fmaxf(bcnt_q[b], 1.f);
  float gm = bsum_g[b * H + c] * ig;
  float gs = sqrtf(fmaxf(bsq_g[b * H + c] * ig - gm * gm, 1e-6f));
  float qm = bsum_q[b * H + c] * iq;
  float qs = sqrtf(fmaxf(bsq_q[b * H + c] * iq - qm * qm, 1e-6f));
  float gl = globb[c];
#pragma unroll
  for (int j = 0; j < GDIM; j++) gl += gf[b * GDIM + j] * globW[j * H + c];
  gl = silu_f(gl);
  comb[c] = gm;
  comb[H + c] = gs;
  comb[2 * H + c] = qm;
  comb[3 * H + c] = qs;
  comb[4 * H + c] = gl;
  if (c == 0) {
    comb[5 * H] = backend[b];
    comb[5 * H + 1] = precision[b];
  }
  __syncthreads();
  float f = bbb[c];
  for (int k = 0; k < 5 * H + 2; k++) f += comb[k] * bbW[k * H + c];
  f = silu_f(f);
  feat[c] = f;
  __syncthreads();
  if (c < 10) {
    float o = thrb[c];
#pragma unroll
    for (int k = 0; k < H; k++) o += feat[k] * thrW[k * 10 + c];
    out[b * 10 + c] = o;
  }
  if (c == 64) {
    float o = runb[0];
    for (int k = 0; k < H; k++) o += feat[k] * runW[k];
    out[NB * 10 + b] = o;
  }
}

// ---------------- launch ----------------

extern "C" void kernel_launch(void* const* d_in, const int* in_sizes, int n_in,
                              void* d_out, int out_size, void* d_ws, size_t ws_size,
                              hipStream_t stream) {
  const int* gate_type = (const int*)d_in[0];
  const int* gate_arity = (const int*)d_in[1];
  const int* gate_dir = (const int*)d_in[2];
  const float* gate_ixn = (const float*)d_in[3];
  const float* qdeg = (const float*)d_in[4];
  const int* src_g2q = (const int*)d_in[5];
  const int* dst_g2q = (const int*)d_in[6];
  const int* src_q2g = (const int*)d_in[7];
  const int* dst_q2g = (const int*)d_in[8];
  const int* gate_batch = (const int*)d_in[9];
  const int* qubit_batch = (const int*)d_in[10];
  const float* gfeat = (const float*)d_in[11];
  const float* backend = (const float*)d_in[12];
  const float* precision = (const float*)d_in[13];
  const float* emb = (const float*)d_in[14];
  const float* gpW = (const float*)d_in[15];
  const float* gpb = (const float*)d_in[16];
  const float* qpW = (const float*)d_in[17];
  const float* qpb = (const float*)d_in[18];
  const float* g2q_ll_W = (const float*)d_in[19];
  const float* g2q_ll_b = (const float*)d_in[20];
  const float* g2q_lr_W = (const float*)d_in[21];
  const float* g2q_lr_b = (const float*)d_in[22];
  const float* q2g_ll_W = (const float*)d_in[23];
  const float* q2g_ll_b = (const float*)d_in[24];
  const float* q2g_lr_W = (const float*)d_in[25];
  const float* q2g_lr_b = (const float*)d_in[26];
  const float* gate_ln_g = (const float*)d_in[27];
  const float* gate_ln_b = (const float*)d_in[28];
  const float* qubit_ln_g = (const float*)d_in[29];
  const float* qubit_ln_b = (const float*)d_in[30];
  const float* globW = (const float*)d_in[31];
  const float* globb = (const float*)d_in[32];
  const float* bbW = (const float*)d_in[33];
  const float* bbb = (const float*)d_in[34];
  const float* thrW = (const float*)d_in[35];
  const float* thrb = (const float*)d_in[36];
  const float* runW = (const float*)d_in[37];
  const float* runb = (const float*)d_in[38];

  char* base = (char*)d_ws;
  u32* gx    = (u32*)base;                         // 128,000,000 B
  u32* qx    = gx + (size_t)NGATE * 64;            //  25,600,000 B
  u32* agg_q = qx + (size_t)NQUB * 64;             //  25,600,000 B
  u16* Whi   = (u16*)(agg_q + (size_t)NQUB * 64);  //     524,288 B
  u16* Wlo   = Whi + 8 * 32768;                    //     524,288 B
  float* bcat = (float*)(Wlo + 8 * 32768);         //       4,096 B
  int* offq = (int*)(bcat + 8 * 128);              // NQUB+1
  int* offg = offq + (NQUB + 1);                   // NGATE+1
  int* csrq = offg + (NGATE + 1);                  // NEDGE
  int* csrg = csrq + NEDGE;                        // NEDGE
  int* cntq = csrg + NEDGE;                        // NQUB
  int* cntg = cntq + NQUB;                         // NGATE
  int* bsumA = cntg + NGATE;                       // 512
  int* bsumB = bsumA + 512;                        // 512
  float* bsum_g = (float*)(bsumB + 512);
  float* bsq_g  = bsum_g + NB * H;
  float* bsum_q = bsq_g + NB * H;
  float* bsq_q  = bsum_q + NB * H;
  float* bcnt_g = bsq_q + NB * H;                  // NB
  float* bcnt_q = bcnt_g + NB;                     // NB
  u32* agg_g = (u32*)(bcnt_q + NB);                // OPTIONAL: 128,000,000 B
  size_t need_fused = (size_t)((char*)(bcnt_q + NB) - base);
  size_t need_split = need_fused + (size_t)NGATE * 64 * sizeof(u32);
  if (ws_size < need_fused) {
    k_sentinel<<<1, 1, 0, stream>>>((float*)d_out);
    return;
  }
  const bool split = (ws_size >= need_split);

  // ---- weight prep (layer-invariant) ----
  k_prep_w<<<(8 * 256 * 128 + 255) / 256, 256, 0, stream>>>(
      g2q_ll_W, g2q_lr_W, q2g_ll_W, q2g_lr_W, Whi, Wlo);
  k_prep_b<<<4, 256, 0, stream>>>(g2q_ll_b, g2q_lr_b, q2g_ll_b, q2g_lr_b, bcat);

  // ---- CSR build (layer-invariant) ----
  hipMemsetAsync(cntq, 0, (size_t)(NQUB + NGATE) * sizeof(int), stream);
  k_count<<<(NEDGE + 255) / 256, 256, 0, stream>>>(dst_g2q, dst_q2g, cntq, cntg);
  const int nbq = (NQUB + 1023) / 1024, nbg = (NGATE + 1023) / 1024;
  k_scan_chunk<<<nbq, 1024, 0, stream>>>(cntq, NQUB, offq + 1, bsumA);
  k_scan_chunk<<<1, 1024, 0, stream>>>(bsumA, nbq, bsumB, nullptr);
  k_scan_add<<<nbq, 1024, 0, stream>>>(NQUB, offq, bsumB);
  k_scan_chunk<<<nbg, 1024, 0, stream>>>(cntg, NGATE, offg + 1, bsumA);
  k_scan_chunk<<<1, 1024, 0, stream>>>(bsumA, nbg, bsumB, nullptr);
  k_scan_add<<<nbg, 1024, 0, stream>>>(NGATE, offg, bsumB);
  hipMemsetAsync(cntq, 0, (size_t)(NQUB + NGATE) * sizeof(int), stream);
  k_csr_fill<<<(NEDGE + 255) / 256, 256, 0, stream>>>(
      src_g2q, dst_g2q, src_q2g, dst_q2g, offq, offg, cntq, cntg, csrq, csrg);

  // ---- batch seg counts + stats init ----
  size_t stats_floats = 4ULL * NB * H + 2ULL * NB;
  hipMemsetAsync(bsum_g, 0, stats_floats * sizeof(float), stream);
  k_seg_counts<<<(NGATE / 64 + 256) / 256, 256, 0, stream>>>(gate_batch, bcnt_g, NGATE);
  k_seg_counts<<<(NQUB / 64 + 256) / 256, 256, 0, stream>>>(qubit_batch, bcnt_q, NQUB);

  // ---- projections ----
  k_gate_proj<<<1024, 256, 0, stream>>>(gate_type, gate_arity, gate_dir, gate_ixn,
                                        emb, gpW, gpb, gx);
  k_qubit_proj<<<(NQUB * 64 + 255) / 256, 256, 0, stream>>>(qdeg, qpW, qpb, qx);

  // ---- layers ----
  const int blocks_g = ((NGATE / 32) + 3) / 4;  // 3907
  const int blocks_q = ((NQUB / 32) + 3) / 4;   // 782
  for (int l = 0; l < NL; l++) {
    const u16* WhiG = Whi + (size_t)(l * 2 + 1) * 32768;
    const u16* WloG = Wlo + (size_t)(l * 2 + 1) * 32768;
    const float* bcG = bcat + (l * 2 + 1) * 128;
    const u16* WhiQ = Whi + (size_t)(l * 2) * 32768;
    const u16* WloQ = Wlo + (size_t)(l * 2) * 32768;
    const float* bcQ = bcat + (l * 2) * 128;
    // agg_q = seg-mean(old gx)   [before gate-side overwrites gx]
    k_gather_rows<<<(NQUB + 3) / 4, 256, 0, stream>>>(gx, offq, csrq, agg_q, NQUB);
    if (split) {
      // agg_g = seg-mean(old qx) [before qubit-side overwrites qx]
      k_gather_rows<<<NGATE / 4, 256, 0, stream>>>(qx, offg, csrg, agg_g, NGATE);
      k_layer<0><<<blocks_g, 256, 0, stream>>>(
          (const u16*)agg_g, nullptr, nullptr, nullptr, gx,
          WhiG, WloG, bcG, gate_ln_g + (size_t)l * H, gate_ln_b + (size_t)l * H, NGATE);
    } else {
      k_layer<1><<<blocks_g, 256, 0, stream>>>(
          nullptr, (const u16*)qx, offg, csrg, gx,
          WhiG, WloG, bcG, gate_ln_g + (size_t)l * H, gate_ln_b + (size_t)l * H, NGATE);
    }
    k_layer<0><<<blocks_q, 256, 0, stream>>>(
        (const u16*)agg_q, nullptr, nullptr, nullptr, qx,
        WhiQ, WloQ, bcQ, qubit_ln_g + (size_t)l * H, qubit_ln_b + (size_t)l * H, NQUB);
  }

  // ---- readout ----
  k_bstats<<<NGATE / 32, 128, 0, stream>>>(gx, gate_batch, bsum_g, bsq_g, NGATE);
  k_bstats<<<NQUB / 32, 128, 0, stream>>>(qx, qubit_batch, bsum_q, bsq_q, NQUB);
  k_head<<<NB, 128, 0, stream>>>(bsum_g, bsq_g, bcnt_g, bsum_q, bsq_q, bcnt_q,
                                 gfeat, backend, precision, globW, globb,
                                 bbW, bbb, thrW, thrb, runW, runb, (float*)d_out);
}

// Round 8
// 1463.290 us; speedup vs baseline: 4.4729x; 1.3806x over previous
//
#include <hip/hip_runtime.h>

// QCircuitBipartiteModel — round 8: LDS-staged B-fragments (double-buffered per-ks).
//  * r7 post-mortem: gate k_layer latency-bound on per-wave B-frag L2 streaming
//    (256 dwordx4 loads/wave interleaved with MFMA; Mfma 8.6%, occ 21%).
//  * B-frags identical across waves -> stage per-ks 16KB (hi+lo) into LDS, 2-buffered
//    (32KB), reg-staged conflict-free writes, ds_read_b128 conflict-free reads,
//    2-iteration global-load slack. A-frags hoisted to registers in prologue.
//  * Tail handling: NO early return (barriers!) — clamped waves (wvalid) join all
//    barriers, stores guarded. nrows % 32 == 0 so waves are all-valid or all-dup.
//  * Everything else identical to r7 (2020us, passed).

#define NGATE 500000
#define NQUB  100000
#define NEDGE 1000000
#define H     128
#define NL    4
#define NB    1024
#define EMB   16
#define GDIM  32
#define NTYPES 31

typedef unsigned int u32;
typedef unsigned short u16;
typedef __attribute__((ext_vector_type(8))) short short8;   // 8 bf16 = 4 VGPR
typedef __attribute__((ext_vector_type(4))) float f32x4;

__device__ __forceinline__ float silu_f(float x) { return x / (1.f + __expf(-x)); }
__device__ __forceinline__ u16 f2bf(float f) {
  u32 x = __float_as_uint(f);
  return (u16)((x + 0x7fffu + ((x >> 16) & 1u)) >> 16);  // RNE
}
__device__ __forceinline__ u32 pack2(float a, float b) {
  return (u32)f2bf(a) | ((u32)f2bf(b) << 16);
}
__device__ __forceinline__ float2 unpack2(u32 v) {
  return make_float2(__uint_as_float((v & 0xffffu) << 16), __uint_as_float((v >> 16) << 16));
}
__device__ __forceinline__ float bf16tof(u16 h) { return __uint_as_float(((u32)h) << 16); }

__global__ void k_sentinel(float* out) { out[0] = 10000.f; }

// ---------------- projections ----------------

__global__ __launch_bounds__(256) void k_gate_proj(
    const int* __restrict__ ty, const int* __restrict__ ar, const int* __restrict__ di,
    const float* __restrict__ ixn, const float* __restrict__ emb,
    const float* __restrict__ W, const float* __restrict__ bias, u32* __restrict__ gx) {
  __shared__ float sW[19 * H];
  __shared__ float se[NTYPES * EMB];
  __shared__ float sb[H];
  for (int i = threadIdx.x; i < 19 * H; i += 256) sW[i] = W[i];
  for (int i = threadIdx.x; i < NTYPES * EMB; i += 256) se[i] = emb[i];
  if (threadIdx.x < H) sb[threadIdx.x] = bias[threadIdx.x];
  __syncthreads();
  const float2* sW2 = (const float2*)sW;
  const float2* sb2 = (const float2*)sb;
  int lane = threadIdx.x & 63, wid = threadIdx.x >> 6;
  int gw = blockIdx.x * 4 + wid, nw = gridDim.x * 4;
  for (int r = gw; r < NGATE; r += nw) {
    int t = ty[r];
    float fa = (float)ar[r], fd = (float)di[r], fi = ixn[r];
    float2 b2v = sb2[lane];
    float al = b2v.x, ah = b2v.y;
#pragma unroll
    for (int k = 0; k < EMB; k++) {
      float e = se[t * EMB + k];
      float2 w = sW2[k * 64 + lane];
      al += e * w.x;
      ah += e * w.y;
    }
    float2 wa = sW2[16 * 64 + lane], wd = sW2[17 * 64 + lane], wi = sW2[18 * 64 + lane];
    al += fa * wa.x + fd * wd.x + fi * wi.x;
    ah += fa * wa.y + fd * wd.y + fi * wi.y;
    gx[(size_t)r * 64 + lane] = pack2(al, ah);
  }
}

__global__ __launch_bounds__(256) void k_qubit_proj(
    const float* __restrict__ deg, const float* __restrict__ W,
    const float* __restrict__ b, u32* __restrict__ qx) {
  int idx = blockIdx.x * 256 + threadIdx.x;
  if (idx >= NQUB * 64) return;
  int r = idx >> 6, l = idx & 63;
  float d = deg[r];
  qx[idx] = pack2(d * W[2 * l] + b[2 * l], d * W[2 * l + 1] + b[2 * l + 1]);
}

// ---------------- CSR build ----------------

__global__ __launch_bounds__(256) void k_count(
    const int* __restrict__ dq, const int* __restrict__ dg,
    int* __restrict__ cq, int* __restrict__ cg) {
  int e = blockIdx.x * 256 + threadIdx.x;
  if (e >= NEDGE) return;
  atomicAdd(&cq[dq[e]], 1);
  atomicAdd(&cg[dg[e]], 1);
}

__global__ __launch_bounds__(1024) void k_scan_chunk(
    const int* __restrict__ cnt, int n, int* __restrict__ out, int* __restrict__ bsum) {
  __shared__ int s[1024];
  int i = blockIdx.x * 1024 + threadIdx.x;
  int v = (i < n) ? cnt[i] : 0;
  s[threadIdx.x] = v;
  __syncthreads();
  for (int d = 1; d < 1024; d <<= 1) {
    int t = (threadIdx.x >= d) ? s[threadIdx.x - d] : 0;
    __syncthreads();
    s[threadIdx.x] += t;
    __syncthreads();
  }
  if (i < n) out[i] = s[threadIdx.x];
  if (threadIdx.x == 1023 && bsum) bsum[blockIdx.x] = s[1023];
}

__global__ __launch_bounds__(1024) void k_scan_add(
    int n, int* __restrict__ off, const int* __restrict__ bscan) {
  int i = blockIdx.x * 1024 + threadIdx.x;
  if (i < n && blockIdx.x > 0) off[i + 1] += bscan[blockIdx.x - 1];
  if (i == 0) off[0] = 0;
}

__global__ __launch_bounds__(256) void k_csr_fill(
    const int* __restrict__ sq, const int* __restrict__ dq,
    const int* __restrict__ sg, const int* __restrict__ dg,
    const int* __restrict__ offq, const int* __restrict__ offg,
    int* __restrict__ fq, int* __restrict__ fg,
    int* __restrict__ csrq, int* __restrict__ csrg) {
  int e = blockIdx.x * 256 + threadIdx.x;
  if (e >= NEDGE) return;
  int d1 = dq[e];
  int p1 = atomicAdd(&fq[d1], 1);
  csrq[offq[d1] + p1] = sq[e];
  int d2 = dg[e];
  int p2 = atomicAdd(&fg[d2], 1);
  csrg[offg[d2] + p2] = sg[e];
}

// ---------------- weight prep: hi/lo bf16 B-frag tables ----------------

__global__ __launch_bounds__(256) void k_prep_w(
    const float* __restrict__ g2q_ll, const float* __restrict__ g2q_lr,
    const float* __restrict__ q2g_ll, const float* __restrict__ q2g_lr,
    u16* __restrict__ Whi, u16* __restrict__ Wlo) {
  int t = blockIdx.x * 256 + threadIdx.x;
  if (t >= 8 * 256 * 128) return;
  int o = t & 127, k = (t >> 7) & 255, mat = t >> 15;
  int l = mat >> 1, side = mat & 1;
  const float* Wll = side ? q2g_ll : g2q_ll;
  const float* Wlr = side ? q2g_lr : g2q_lr;
  float w = (k < 128) ? Wll[((size_t)l * 128 + k) * 128 + o]
                      : Wlr[((size_t)l * 128 + (k - 128)) * 128 + o];
  u16 hi = f2bf(w);
  float lof = w - bf16tof(hi);
  int ks = k >> 5, kr = k & 31, ot = o >> 4;
  int lane = ((kr >> 3) << 4) | (o & 15);
  int j = kr & 7;
  size_t pos = (((size_t)(mat * 8 + ks) * 8 + ot) * 64 + lane) * 8 + j;
  Whi[pos] = hi;
  Wlo[pos] = f2bf(lof);
}

__global__ __launch_bounds__(256) void k_prep_b(
    const float* __restrict__ g2q_llb, const float* __restrict__ g2q_lrb,
    const float* __restrict__ q2g_llb, const float* __restrict__ q2g_lrb,
    float* __restrict__ bcat) {
  int t = blockIdx.x * 256 + threadIdx.x;
  if (t >= 8 * 128) return;
  int c = t & 127, mat = t >> 7, l = mat >> 1, side = mat & 1;
  bcat[t] = side ? (q2g_llb[l * 128 + c] + q2g_lrb[l * 128 + c])
                 : (g2q_llb[l * 128 + c] + g2q_lrb[l * 128 + c]);
}

// ---------------- seg-mean gather: wave per row, 4-way unrolled edge walk ----------------

__global__ __launch_bounds__(256) void k_gather_rows(
    const u32* __restrict__ SRC, const int* __restrict__ off, const int* __restrict__ csr,
    u32* __restrict__ OUT, int n) {
  int lane = threadIdx.x & 63, wid = threadIdx.x >> 6;
  int w = blockIdx.x * 4 + wid, nw = gridDim.x * 4;
  for (int r = w; r < n; r += nw) {
    int b = off[r], e = off[r + 1];
    float sl = 0.f, sh = 0.f;
    for (int t = b; t < e; t += 4) {
      int t1 = min(t + 1, e - 1), t2 = min(t + 2, e - 1), t3 = min(t + 3, e - 1);
      float w1 = (t + 1 < e) ? 1.f : 0.f;
      float w2 = (t + 2 < e) ? 1.f : 0.f;
      float w3 = (t + 3 < e) ? 1.f : 0.f;
      u32 v0 = SRC[(size_t)csr[t] * 64 + lane];
      u32 v1 = SRC[(size_t)csr[t1] * 64 + lane];
      u32 v2 = SRC[(size_t)csr[t2] * 64 + lane];
      u32 v3 = SRC[(size_t)csr[t3] * 64 + lane];
      float2 f0 = unpack2(v0), f1 = unpack2(v1), f2 = unpack2(v2), f3 = unpack2(v3);
      sl += f0.x + w1 * f1.x + w2 * f2.x + w3 * f3.x;
      sh += f0.y + w1 * f1.y + w2 * f2.y + w3 * f3.y;
    }
    float inv = 1.f / fmaxf((float)(e - b), 1.f);
    OUT[(size_t)r * 64 + lane] = pack2(sl * inv, sh * inv);
  }
}

// ---------------- fused layer update (MFMA), 32 rows/wave, LDS-staged B ----------------
// X := LN(silu([AGG | X] @ Wcat + bcat)) * lng + lnb + X
// B-frags staged per-ks (16KB hi+lo) into double-buffered LDS; all 4 waves share.
// GATHER=0: AGG from dense buffer. GATHER=1: AGG = CSR gather-mean (2-way unrolled).
// nrows % 32 == 0. Tail waves clamp (wvalid) but keep barrier participation.

template <int GATHER>
__global__ __launch_bounds__(256, 2) void k_layer(
    const u16* __restrict__ AGG16, const u16* __restrict__ SRC16,
    const int* __restrict__ off, const int* __restrict__ csr,
    u32* __restrict__ X, const u16* __restrict__ Whi, const u16* __restrict__ Wlo,
    const float* __restrict__ bcat, const float* __restrict__ lng,
    const float* __restrict__ lnb, int nrows) {
  __shared__ __align__(16) u16 sB[2][2][4096];  // [buf][hi/lo][8KB slice]
  int tid = threadIdx.x;
  int lane = tid & 63, wid = tid >> 6;
  long wt = (long)blockIdx.x * 4 + wid;
  long r0 = wt * 32;
  bool wvalid = (r0 < nrows);
  long r0c = wvalid ? r0 : 0;
  int rlo = lane & 15, khi = lane >> 4;
  u16* X16 = (u16*)X;

  uint4 h0, h1, l0, l1;
#define LOADB(KS) { \
    const uint4* sh_ = (const uint4*)(Whi + (size_t)(KS) * 4096); \
    const uint4* sl_ = (const uint4*)(Wlo + (size_t)(KS) * 4096); \
    h0 = sh_[tid]; h1 = sh_[256 + tid]; l0 = sl_[tid]; l1 = sl_[256 + tid]; }
#define WRITEB(BUF) { \
    ((uint4*)sB[BUF][0])[tid] = h0; ((uint4*)sB[BUF][0])[256 + tid] = h1; \
    ((uint4*)sB[BUF][1])[tid] = l0; ((uint4*)sB[BUF][1])[256 + tid] = l1; }

  LOADB(0);
  WRITEB(0);
  LOADB(1);

  // ---- A-frags: aggregate half (ag) + X half (xg), all in registers
  short8 ag[2][4], xg[2][4];
#pragma unroll
  for (int rs = 0; rs < 2; rs++) {
    long row = r0c + rs * 16 + rlo;
#pragma unroll
    for (int ks = 0; ks < 4; ks++)
      xg[rs][ks] = *(const short8*)(X16 + row * 128 + ks * 32 + khi * 8);
    if (GATHER == 0) {
#pragma unroll
      for (int ks = 0; ks < 4; ks++)
        ag[rs][ks] = *(const short8*)(AGG16 + row * 128 + ks * 32 + khi * 8);
    } else {
      int bgn = off[row], end = off[row + 1];
      float m[4][8];
#pragma unroll
      for (int ks = 0; ks < 4; ks++)
#pragma unroll
        for (int j = 0; j < 8; j++) m[ks][j] = 0.f;
      for (int t = bgn; t < end; t += 2) {
        int t1 = min(t + 1, end - 1);
        float w1 = (t + 1 < end) ? 1.f : 0.f;
        const u16* p0 = SRC16 + (size_t)csr[t] * 128 + khi * 8;
        const u16* p1 = SRC16 + (size_t)csr[t1] * 128 + khi * 8;
        uint4 va[4] = {*(const uint4*)(p0), *(const uint4*)(p0 + 32),
                       *(const uint4*)(p0 + 64), *(const uint4*)(p0 + 96)};
        uint4 vb[4] = {*(const uint4*)(p1), *(const uint4*)(p1 + 32),
                       *(const uint4*)(p1 + 64), *(const uint4*)(p1 + 96)};
#pragma unroll
        for (int ks = 0; ks < 4; ks++) {
          m[ks][0] += __uint_as_float((va[ks].x & 0xffffu) << 16) + w1 * __uint_as_float((vb[ks].x & 0xffffu) << 16);
          m[ks][1] += __uint_as_float((va[ks].x >> 16) << 16) + w1 * __uint_as_float((vb[ks].x >> 16) << 16);
          m[ks][2] += __uint_as_float((va[ks].y & 0xffffu) << 16) + w1 * __uint_as_float((vb[ks].y & 0xffffu) << 16);
          m[ks][3] += __uint_as_float((va[ks].y >> 16) << 16) + w1 * __uint_as_float((vb[ks].y >> 16) << 16);
          m[ks][4] += __uint_as_float((va[ks].z & 0xffffu) << 16) + w1 * __uint_as_float((vb[ks].z & 0xffffu) << 16);
          m[ks][5] += __uint_as_float((va[ks].z >> 16) << 16) + w1 * __uint_as_float((vb[ks].z >> 16) << 16);
          m[ks][6] += __uint_as_float((va[ks].w & 0xffffu) << 16) + w1 * __uint_as_float((vb[ks].w & 0xffffu) << 16);
          m[ks][7] += __uint_as_float((va[ks].w >> 16) << 16) + w1 * __uint_as_float((vb[ks].w >> 16) << 16);
        }
      }
      float inv = 1.f / fmaxf((float)(end - bgn), 1.f);
#pragma unroll
      for (int ks = 0; ks < 4; ks++) {
        short8 af;
#pragma unroll
        for (int j = 0; j < 8; j++) af[j] = (short)f2bf(m[ks][j] * inv);
        ag[rs][ks] = af;
      }
    }
  }

  __syncthreads();  // sB[0] ready

  // ---- MFMA main loop: K = 256 (8 ks), O = 128 (8 ot); B from LDS
  f32x4 acc[2][8];
#pragma unroll
  for (int rs = 0; rs < 2; rs++)
#pragma unroll
    for (int ot = 0; ot < 8; ot++) acc[rs][ot] = (f32x4){0.f, 0.f, 0.f, 0.f};

#pragma unroll
  for (int ks = 0; ks < 8; ks++) {
    const u16* sH = sB[ks & 1][0];
    const u16* sL = sB[ks & 1][1];
    short8 a0 = (ks < 4) ? ag[0][ks & 3] : xg[0][ks & 3];
    short8 a1 = (ks < 4) ? ag[1][ks & 3] : xg[1][ks & 3];
#pragma unroll
    for (int ot = 0; ot < 8; ot++) {
      short8 bh = *(const short8*)(sH + ot * 512 + lane * 8);
      short8 bl = *(const short8*)(sL + ot * 512 + lane * 8);
      acc[0][ot] = __builtin_amdgcn_mfma_f32_16x16x32_bf16(a0, bh, acc[0][ot], 0, 0, 0);
      acc[0][ot] = __builtin_amdgcn_mfma_f32_16x16x32_bf16(a0, bl, acc[0][ot], 0, 0, 0);
      acc[1][ot] = __builtin_amdgcn_mfma_f32_16x16x32_bf16(a1, bh, acc[1][ot], 0, 0, 0);
      acc[1][ot] = __builtin_amdgcn_mfma_f32_16x16x32_bf16(a1, bl, acc[1][ot], 0, 0, 0);
    }
    if (ks < 7) {
      WRITEB((ks + 1) & 1);
      if (ks < 6) LOADB(ks + 2);
      __syncthreads();
    }
  }
#undef LOADB
#undef WRITEB

  // ---- epilogue: bias -> silu -> LN (16-lane-group reduce) -> residual -> store
  if (!wvalid) return;  // no barriers below
  float bz[8], lg[8], lb[8];
#pragma unroll
  for (int ot = 0; ot < 8; ot++) {
    int c = ot * 16 + rlo;
    bz[ot] = bcat[c];
    lg[ot] = lng[c];
    lb[ot] = lnb[c];
  }
#pragma unroll
  for (int rs = 0; rs < 2; rs++) {
#pragma unroll
    for (int i = 0; i < 4; i++) {
      long row = r0 + rs * 16 + khi * 4 + i;
      float u[8], s1 = 0.f, s2 = 0.f;
#pragma unroll
      for (int ot = 0; ot < 8; ot++) {
        float z = acc[rs][ot][i] + bz[ot];
        float uu = silu_f(z);
        u[ot] = uu;
        s1 += uu;
        s2 += uu * uu;
      }
#pragma unroll
      for (int msk = 1; msk < 16; msk <<= 1) {
        s1 += __shfl_xor(s1, msk, 64);
        s2 += __shfl_xor(s2, msk, 64);
      }
      float mean = s1 * (1.f / 128.f);
      float var = s2 * (1.f / 128.f) - mean * mean;
      float rsq = rsqrtf(var + 1e-5f);
#pragma unroll
      for (int ot = 0; ot < 8; ot++) {
        size_t idx = (size_t)row * 128 + ot * 16 + rlo;
        float xr = bf16tof(X16[idx]);
        float o = (u[ot] - mean) * rsq * lg[ot] + lb[ot] + xr;
        X16[idx] = f2bf(o);
      }
    }
  }
}

// ---------------- batch stats / head ----------------

__global__ __launch_bounds__(256) void k_seg_counts(
    const int* __restrict__ batch, float* __restrict__ bcnt, int n) {
  int t = blockIdx.x * 256 + threadIdx.x;
  int r0 = t * 64;
  if (r0 >= n) return;
  int end = min(r0 + 64, n);
  int cur = batch[r0];
  float c = 0.f;
  for (int r = r0; r < end; r++) {
    int b = batch[r];
    if (b != cur) { atomicAdd(&bcnt[cur], c); cur = b; c = 0.f; }
    c += 1.f;
  }
  atomicAdd(&bcnt[cur], c);
}

__global__ __launch_bounds__(128) void k_bstats(
    const u32* __restrict__ X, const int* __restrict__ batch,
    float* __restrict__ bsum, float* __restrict__ bsq, int nrows) {
  __shared__ int sb[32];
  int r0 = blockIdx.x * 32;
  int c = threadIdx.x;
  if (c < 32) sb[c] = (r0 + c < nrows) ? batch[r0 + c] : -1;
  __syncthreads();
  float s = 0.f, q = 0.f;
  int cur = sb[0];
  const u16* Xh = (const u16*)X;
  for (int i = 0; i < 32; i++) {
    int r = r0 + i;
    if (r >= nrows) break;
    int b = sb[i];
    if (b != cur) {
      atomicAdd(&bsum[cur * H + c], s);
      atomicAdd(&bsq[cur * H + c], q);
      s = 0.f; q = 0.f; cur = b;
    }
    float v = bf16tof(Xh[(size_t)r * H + c]);
    s += v;
    q += v * v;
  }
  atomicAdd(&bsum[cur * H + c], s);
  atomicAdd(&bsq[cur * H + c], q);
}

__global__ __launch_bounds__(128) void k_head(
    const float* __restrict__ bsum_g, const float* __restrict__ bsq_g, const float* __restrict__ bcnt_g,
    const float* __restrict__ bsum_q, const float* __restrict__ bsq_q, const float* __restrict__ bcnt_q,
    const float* __restrict__ gf, const float* __restrict__ backend, const float* __restrict__ precision,
    const float* __restrict__ globW, const float* __restrict__ globb,
    const float* __restrict__ bbW, const float* __restrict__ bbb,
    const float* __restrict__ thrW, const float* __restrict__ thrb,
    const float* __restrict__ runW, const float* __restrict__ runb,
    float* __restrict__ out) {
  __shared__ float comb[5 * H + 2];
  __shared__ float feat[H];
  int b = blockIdx.x, c = threadIdx.x;
  float ig = 1.f / fmaxf(bcnt_g[b], 1.f);
  float iq = 1.f / fmaxf(bcnt_q[b], 1.f);
  float gm = bsum_g[b * H + c] * ig;
  float gs = sqrtf(fmaxf(bsq_g[b * H + c] * ig - gm * gm, 1e-6f));
  float qm = bsum_q[b * H + c] * iq;
  float qs = sqrtf(fmaxf(bsq_q[b * H + c] * iq - qm * qm, 1e-6f));
  float gl = globb[c];
#pragma unroll
  for (int j = 0; j < GDIM; j++) gl += gf[b * GDIM + j] * globW[j * H + c];
  gl = silu_f(gl);
  comb[c] = gm;
  comb[H + c] = gs;
  comb[2 * H + c] = qm;
  comb[3 * H + c] = qs;
  comb[4 * H + c] = gl;
  if (c == 0) {
    comb[5 * H] = backend[b];
    comb[5 * H + 1] = precision[b];
  }
  __syncthreads();
  float f = bbb[c];
  for (int k = 0; k < 5 * H + 2; k++) f += comb[k] * bbW[k * H + c];
  f = silu_f(f);
  feat[c] = f;
  __syncthreads();
  if (c < 10) {
    float o = thrb[c];
#pragma unroll
    for (int k = 0; k < H; k++) o += feat[k] * thrW[k * 10 + c];
    out[b * 10 + c] = o;
  }
  if (c == 64) {
    float o = runb[0];
    for (int k = 0; k < H; k++) o += feat[k] * runW[k];
    out[NB * 10 + b] = o;
  }
}

// ---------------- launch ----------------

extern "C" void kernel_launch(void* const* d_in, const int* in_sizes, int n_in,
                              void* d_out, int out_size, void* d_ws, size_t ws_size,
                              hipStream_t stream) {
  const int* gate_type = (const int*)d_in[0];
  const int* gate_arity = (const int*)d_in[1];
  const int* gate_dir = (const int*)d_in[2];
  const float* gate_ixn = (const float*)d_in[3];
  const float* qdeg = (const float*)d_in[4];
  const int* src_g2q = (const int*)d_in[5];
  const int* dst_g2q = (const int*)d_in[6];
  const int* src_q2g = (const int*)d_in[7];
  const int* dst_q2g = (const int*)d_in[8];
  const int* gate_batch = (const int*)d_in[9];
  const int* qubit_batch = (const int*)d_in[10];
  const float* gfeat = (const float*)d_in[11];
  const float* backend = (const float*)d_in[12];
  const float* precision = (const float*)d_in[13];
  const float* emb = (const float*)d_in[14];
  const float* gpW = (const float*)d_in[15];
  const float* gpb = (const float*)d_in[16];
  const float* qpW = (const float*)d_in[17];
  const float* qpb = (const float*)d_in[18];
  const float* g2q_ll_W = (const float*)d_in[19];
  const float* g2q_ll_b = (const float*)d_in[20];
  const float* g2q_lr_W = (const float*)d_in[21];
  const float* g2q_lr_b = (const float*)d_in[22];
  const float* q2g_ll_W = (const float*)d_in[23];
  const float* q2g_ll_b = (const float*)d_in[24];
  const float* q2g_lr_W = (const float*)d_in[25];
  const float* q2g_lr_b = (const float*)d_in[26];
  const float* gate_ln_g = (const float*)d_in[27];
  const float* gate_ln_b = (const float*)d_in[28];
  const float* qubit_ln_g = (const float*)d_in[29];
  const float* qubit_ln_b = (const float*)d_in[30];
  const float* globW = (const float*)d_in[31];
  const float* globb = (const float*)d_in[32];
  const float* bbW = (const float*)d_in[33];
  const float* bbb = (const float*)d_in[34];
  const float* thrW = (const float*)d_in[35];
  const float* thrb = (const float*)d_in[36];
  const float* runW = (const float*)d_in[37];
  const float* runb = (const float*)d_in[38];

  char* base = (char*)d_ws;
  u32* gx    = (u32*)base;                         // 128,000,000 B
  u32* qx    = gx + (size_t)NGATE * 64;            //  25,600,000 B
  u32* agg_q = qx + (size_t)NQUB * 64;             //  25,600,000 B
  u16* Whi   = (u16*)(agg_q + (size_t)NQUB * 64);  //     524,288 B
  u16* Wlo   = Whi + 8 * 32768;                    //     524,288 B
  float* bcat = (float*)(Wlo + 8 * 32768);         //       4,096 B
  int* offq = (int*)(bcat + 8 * 128);              // NQUB+1
  int* offg = offq + (NQUB + 1);                   // NGATE+1
  int* csrq = offg + (NGATE + 1);                  // NEDGE
  int* csrg = csrq + NEDGE;                        // NEDGE
  int* cntq = csrg + NEDGE;                        // NQUB
  int* cntg = cntq + NQUB;                         // NGATE
  int* bsumA = cntg + NGATE;                       // 512
  int* bsumB = bsumA + 512;                        // 512
  float* bsum_g = (float*)(bsumB + 512);
  float* bsq_g  = bsum_g + NB * H;
  float* bsum_q = bsq_g + NB * H;
  float* bsq_q  = bsum_q + NB * H;
  float* bcnt_g = bsq_q + NB * H;                  // NB
  float* bcnt_q = bcnt_g + NB;                     // NB
  u32* agg_g = (u32*)(bcnt_q + NB);                // OPTIONAL: 128,000,000 B
  size_t need_fused = (size_t)((char*)(bcnt_q + NB) - base);
  size_t need_split = need_fused + (size_t)NGATE * 64 * sizeof(u32);
  if (ws_size < need_fused) {
    k_sentinel<<<1, 1, 0, stream>>>((float*)d_out);
    return;
  }
  const bool split = (ws_size >= need_split);

  // ---- weight prep (layer-invariant) ----
  k_prep_w<<<(8 * 256 * 128 + 255) / 256, 256, 0, stream>>>(
      g2q_ll_W, g2q_lr_W, q2g_ll_W, q2g_lr_W, Whi, Wlo);
  k_prep_b<<<4, 256, 0, stream>>>(g2q_ll_b, g2q_lr_b, q2g_ll_b, q2g_lr_b, bcat);

  // ---- CSR build (layer-invariant) ----
  hipMemsetAsync(cntq, 0, (size_t)(NQUB + NGATE) * sizeof(int), stream);
  k_count<<<(NEDGE + 255) / 256, 256, 0, stream>>>(dst_g2q, dst_q2g, cntq, cntg);
  const int nbq = (NQUB + 1023) / 1024, nbg = (NGATE + 1023) / 1024;
  k_scan_chunk<<<nbq, 1024, 0, stream>>>(cntq, NQUB, offq + 1, bsumA);
  k_scan_chunk<<<1, 1024, 0, stream>>>(bsumA, nbq, bsumB, nullptr);
  k_scan_add<<<nbq, 1024, 0, stream>>>(NQUB, offq, bsumB);
  k_scan_chunk<<<nbg, 1024, 0, stream>>>(cntg, NGATE, offg + 1, bsumA);
  k_scan_chunk<<<1, 1024, 0, stream>>>(bsumA, nbg, bsumB, nullptr);
  k_scan_add<<<nbg, 1024, 0, stream>>>(NGATE, offg, bsumB);
  hipMemsetAsync(cntq, 0, (size_t)(NQUB + NGATE) * sizeof(int), stream);
  k_csr_fill<<<(NEDGE + 255) / 256, 256, 0, stream>>>(
      src_g2q, dst_g2q, src_q2g, dst_q2g, offq, offg, cntq, cntg, csrq, csrg);

  // ---- batch seg counts + stats init ----
  size_t stats_floats = 4ULL * NB * H + 2ULL * NB;
  hipMemsetAsync(bsum_g, 0, stats_floats * sizeof(float), stream);
  k_seg_counts<<<(NGATE / 64 + 256) / 256, 256, 0, stream>>>(gate_batch, bcnt_g, NGATE);
  k_seg_counts<<<(NQUB / 64 + 256) / 256, 256, 0, stream>>>(qubit_batch, bcnt_q, NQUB);

  // ---- projections ----
  k_gate_proj<<<1024, 256, 0, stream>>>(gate_type, gate_arity, gate_dir, gate_ixn,
                                        emb, gpW, gpb, gx);
  k_qubit_proj<<<(NQUB * 64 + 255) / 256, 256, 0, stream>>>(qdeg, qpW, qpb, qx);

  // ---- layers ----
  const int blocks_g = (NGATE + 127) / 128;  // 3907
  const int blocks_q = (NQUB + 127) / 128;   // 782
  for (int l = 0; l < NL; l++) {
    const u16* WhiG = Whi + (size_t)(l * 2 + 1) * 32768;
    const u16* WloG = Wlo + (size_t)(l * 2 + 1) * 32768;
    const float* bcG = bcat + (l * 2 + 1) * 128;
    const u16* WhiQ = Whi + (size_t)(l * 2) * 32768;
    const u16* WloQ = Wlo + (size_t)(l * 2) * 32768;
    const float* bcQ = bcat + (l * 2) * 128;
    // agg_q = seg-mean(old gx)   [before gate-side overwrites gx]
    k_gather_rows<<<(NQUB + 3) / 4, 256, 0, stream>>>(gx, offq, csrq, agg_q, NQUB);
    if (split) {
      // agg_g = seg-mean(old qx) [before qubit-side overwrites qx]
      k_gather_rows<<<NGATE / 4, 256, 0, stream>>>(qx, offg, csrg, agg_g, NGATE);
      k_layer<0><<<blocks_g, 256, 0, stream>>>(
          (const u16*)agg_g, nullptr, nullptr, nullptr, gx,
          WhiG, WloG, bcG, gate_ln_g + (size_t)l * H, gate_ln_b + (size_t)l * H, NGATE);
    } else {
      k_layer<1><<<blocks_g, 256, 0, stream>>>(
          nullptr, (const u16*)qx, offg, csrg, gx,
          WhiG, WloG, bcG, gate_ln_g + (size_t)l * H, gate_ln_b + (size_t)l * H, NGATE);
    }
    k_layer<0><<<blocks_q, 256, 0, stream>>>(
        (const u16*)agg_q, nullptr, nullptr, nullptr, qx,
        WhiQ, WloQ, bcQ, qubit_ln_g + (size_t)l * H, qubit_ln_b + (size_t)l * H, NQUB);
  }

  // ---- readout ----
  k_bstats<<<NGATE / 32, 128, 0, stream>>>(gx, gate_batch, bsum_g, bsq_g, NGATE);
  k_bstats<<<NQUB / 32, 128, 0, stream>>>(qx, qubit_batch, bsum_q, bsq_q, NQUB);
  k_head<<<NB, 128, 0, stream>>>(bsum_g, bsq_g, bcnt_g, bsum_q, bsq_q, bcnt_q,
                                 gfeat, backend, precision, globW, globb,
                                 bbW, bbb, thrW, thrb, runW, runb, (float*)d_out);
}

// Round 9
// 1347.070 us; speedup vs baseline: 4.8588x; 1.0863x over previous
//
#include <hip/hip_runtime.h>
#include <hip/hip_bf16.h>

// QCircuitBipartiteModel — round 9: fused gate gather + native bf16 converts.
//  * r8 post-mortem: LDS B-staging delivered (gate 310->186us). Remaining fat:
//    agg_g materialization = 253MB HBM round trip/layer + pushes working set past
//    the 256MB L3 (FETCH rose 184->238MB). MFMA 15% (not the limit), VALU 45%
//    (hand-rolled 4-op RNE f2bf x64/thread).
//  * Gate side -> k_layer<1> (fused CSR gather, B still LDS-staged): no agg_g buffer,
//    working set ~180MB < L3 so random gather reads become L3 hits.
//  * f2bf via __float2bfloat16 (RNE) -> compiler emits v_cvt_pk_bf16_f32 pairs.
//  * ws back to ~207MB. Everything else = r8 (passed, 1463us).

#define NGATE 500000
#define NQUB  100000
#define NEDGE 1000000
#define H     128
#define NL    4
#define NB    1024
#define EMB   16
#define GDIM  32
#define NTYPES 31

typedef unsigned int u32;
typedef unsigned short u16;
typedef __attribute__((ext_vector_type(8))) short short8;   // 8 bf16 = 4 VGPR
typedef __attribute__((ext_vector_type(4))) float f32x4;

__device__ __forceinline__ float silu_f(float x) { return x / (1.f + __expf(-x)); }
__device__ __forceinline__ u16 f2bf(float f) {
  __hip_bfloat16 h = __float2bfloat16(f);   // RNE; compiler fuses pairs to v_cvt_pk_bf16_f32
  u16 r;
  __builtin_memcpy(&r, &h, 2);
  return r;
}
__device__ __forceinline__ u32 pack2(float a, float b) {
  return (u32)f2bf(a) | ((u32)f2bf(b) << 16);
}
__device__ __forceinline__ float2 unpack2(u32 v) {
  return make_float2(__uint_as_float((v & 0xffffu) << 16), __uint_as_float((v >> 16) << 16));
}
__device__ __forceinline__ float bf16tof(u16 h) { return __uint_as_float(((u32)h) << 16); }

__global__ void k_sentinel(float* out) { out[0] = 10000.f; }

// ---------------- projections ----------------

__global__ __launch_bounds__(256) void k_gate_proj(
    const int* __restrict__ ty, const int* __restrict__ ar, const int* __restrict__ di,
    const float* __restrict__ ixn, const float* __restrict__ emb,
    const float* __restrict__ W, const float* __restrict__ bias, u32* __restrict__ gx) {
  __shared__ float sW[19 * H];
  __shared__ float se[NTYPES * EMB];
  __shared__ float sb[H];
  for (int i = threadIdx.x; i < 19 * H; i += 256) sW[i] = W[i];
  for (int i = threadIdx.x; i < NTYPES * EMB; i += 256) se[i] = emb[i];
  if (threadIdx.x < H) sb[threadIdx.x] = bias[threadIdx.x];
  __syncthreads();
  const float2* sW2 = (const float2*)sW;
  const float2* sb2 = (const float2*)sb;
  int lane = threadIdx.x & 63, wid = threadIdx.x >> 6;
  int gw = blockIdx.x * 4 + wid, nw = gridDim.x * 4;
  for (int r = gw; r < NGATE; r += nw) {
    int t = ty[r];
    float fa = (float)ar[r], fd = (float)di[r], fi = ixn[r];
    float2 b2v = sb2[lane];
    float al = b2v.x, ah = b2v.y;
#pragma unroll
    for (int k = 0; k < EMB; k++) {
      float e = se[t * EMB + k];
      float2 w = sW2[k * 64 + lane];
      al += e * w.x;
      ah += e * w.y;
    }
    float2 wa = sW2[16 * 64 + lane], wd = sW2[17 * 64 + lane], wi = sW2[18 * 64 + lane];
    al += fa * wa.x + fd * wd.x + fi * wi.x;
    ah += fa * wa.y + fd * wd.y + fi * wi.y;
    gx[(size_t)r * 64 + lane] = pack2(al, ah);
  }
}

__global__ __launch_bounds__(256) void k_qubit_proj(
    const float* __restrict__ deg, const float* __restrict__ W,
    const float* __restrict__ b, u32* __restrict__ qx) {
  int idx = blockIdx.x * 256 + threadIdx.x;
  if (idx >= NQUB * 64) return;
  int r = idx >> 6, l = idx & 63;
  float d = deg[r];
  qx[idx] = pack2(d * W[2 * l] + b[2 * l], d * W[2 * l + 1] + b[2 * l + 1]);
}

// ---------------- CSR build ----------------

__global__ __launch_bounds__(256) void k_count(
    const int* __restrict__ dq, const int* __restrict__ dg,
    int* __restrict__ cq, int* __restrict__ cg) {
  int e = blockIdx.x * 256 + threadIdx.x;
  if (e >= NEDGE) return;
  atomicAdd(&cq[dq[e]], 1);
  atomicAdd(&cg[dg[e]], 1);
}

__global__ __launch_bounds__(1024) void k_scan_chunk(
    const int* __restrict__ cnt, int n, int* __restrict__ out, int* __restrict__ bsum) {
  __shared__ int s[1024];
  int i = blockIdx.x * 1024 + threadIdx.x;
  int v = (i < n) ? cnt[i] : 0;
  s[threadIdx.x] = v;
  __syncthreads();
  for (int d = 1; d < 1024; d <<= 1) {
    int t = (threadIdx.x >= d) ? s[threadIdx.x - d] : 0;
    __syncthreads();
    s[threadIdx.x] += t;
    __syncthreads();
  }
  if (i < n) out[i] = s[threadIdx.x];
  if (threadIdx.x == 1023 && bsum) bsum[blockIdx.x] = s[1023];
}

__global__ __launch_bounds__(1024) void k_scan_add(
    int n, int* __restrict__ off, const int* __restrict__ bscan) {
  int i = blockIdx.x * 1024 + threadIdx.x;
  if (i < n && blockIdx.x > 0) off[i + 1] += bscan[blockIdx.x - 1];
  if (i == 0) off[0] = 0;
}

__global__ __launch_bounds__(256) void k_csr_fill(
    const int* __restrict__ sq, const int* __restrict__ dq,
    const int* __restrict__ sg, const int* __restrict__ dg,
    const int* __restrict__ offq, const int* __restrict__ offg,
    int* __restrict__ fq, int* __restrict__ fg,
    int* __restrict__ csrq, int* __restrict__ csrg) {
  int e = blockIdx.x * 256 + threadIdx.x;
  if (e >= NEDGE) return;
  int d1 = dq[e];
  int p1 = atomicAdd(&fq[d1], 1);
  csrq[offq[d1] + p1] = sq[e];
  int d2 = dg[e];
  int p2 = atomicAdd(&fg[d2], 1);
  csrg[offg[d2] + p2] = sg[e];
}

// ---------------- weight prep: hi/lo bf16 B-frag tables ----------------

__global__ __launch_bounds__(256) void k_prep_w(
    const float* __restrict__ g2q_ll, const float* __restrict__ g2q_lr,
    const float* __restrict__ q2g_ll, const float* __restrict__ q2g_lr,
    u16* __restrict__ Whi, u16* __restrict__ Wlo) {
  int t = blockIdx.x * 256 + threadIdx.x;
  if (t >= 8 * 256 * 128) return;
  int o = t & 127, k = (t >> 7) & 255, mat = t >> 15;
  int l = mat >> 1, side = mat & 1;
  const float* Wll = side ? q2g_ll : g2q_ll;
  const float* Wlr = side ? q2g_lr : g2q_lr;
  float w = (k < 128) ? Wll[((size_t)l * 128 + k) * 128 + o]
                      : Wlr[((size_t)l * 128 + (k - 128)) * 128 + o];
  u16 hi = f2bf(w);
  float lof = w - bf16tof(hi);
  int ks = k >> 5, kr = k & 31, ot = o >> 4;
  int lane = ((kr >> 3) << 4) | (o & 15);
  int j = kr & 7;
  size_t pos = (((size_t)(mat * 8 + ks) * 8 + ot) * 64 + lane) * 8 + j;
  Whi[pos] = hi;
  Wlo[pos] = f2bf(lof);
}

__global__ __launch_bounds__(256) void k_prep_b(
    const float* __restrict__ g2q_llb, const float* __restrict__ g2q_lrb,
    const float* __restrict__ q2g_llb, const float* __restrict__ q2g_lrb,
    float* __restrict__ bcat) {
  int t = blockIdx.x * 256 + threadIdx.x;
  if (t >= 8 * 128) return;
  int c = t & 127, mat = t >> 7, l = mat >> 1, side = mat & 1;
  bcat[t] = side ? (q2g_llb[l * 128 + c] + q2g_lrb[l * 128 + c])
                 : (g2q_llb[l * 128 + c] + g2q_lrb[l * 128 + c]);
}

// ---------------- seg-mean gather: wave per row, 4-way unrolled edge walk ----------------

__global__ __launch_bounds__(256) void k_gather_rows(
    const u32* __restrict__ SRC, const int* __restrict__ off, const int* __restrict__ csr,
    u32* __restrict__ OUT, int n) {
  int lane = threadIdx.x & 63, wid = threadIdx.x >> 6;
  int w = blockIdx.x * 4 + wid, nw = gridDim.x * 4;
  for (int r = w; r < n; r += nw) {
    int b = off[r], e = off[r + 1];
    float sl = 0.f, sh = 0.f;
    for (int t = b; t < e; t += 4) {
      int t1 = min(t + 1, e - 1), t2 = min(t + 2, e - 1), t3 = min(t + 3, e - 1);
      float w1 = (t + 1 < e) ? 1.f : 0.f;
      float w2 = (t + 2 < e) ? 1.f : 0.f;
      float w3 = (t + 3 < e) ? 1.f : 0.f;
      u32 v0 = SRC[(size_t)csr[t] * 64 + lane];
      u32 v1 = SRC[(size_t)csr[t1] * 64 + lane];
      u32 v2 = SRC[(size_t)csr[t2] * 64 + lane];
      u32 v3 = SRC[(size_t)csr[t3] * 64 + lane];
      float2 f0 = unpack2(v0), f1 = unpack2(v1), f2 = unpack2(v2), f3 = unpack2(v3);
      sl += f0.x + w1 * f1.x + w2 * f2.x + w3 * f3.x;
      sh += f0.y + w1 * f1.y + w2 * f2.y + w3 * f3.y;
    }
    float inv = 1.f / fmaxf((float)(e - b), 1.f);
    OUT[(size_t)r * 64 + lane] = pack2(sl * inv, sh * inv);
  }
}

// ---------------- fused layer update (MFMA), 32 rows/wave, LDS-staged B ----------------
// X := LN(silu([AGG | X] @ Wcat + bcat)) * lng + lnb + X
// B-frags staged per-ks (16KB hi+lo) into double-buffered LDS; all 4 waves share.
// GATHER=0: AGG from dense buffer. GATHER=1: AGG = CSR gather-mean (2-way unrolled).
// nrows % 32 == 0. Tail waves clamp (wvalid) but keep barrier participation.

template <int GATHER>
__global__ __launch_bounds__(256, 2) void k_layer(
    const u16* __restrict__ AGG16, const u16* __restrict__ SRC16,
    const int* __restrict__ off, const int* __restrict__ csr,
    u32* __restrict__ X, const u16* __restrict__ Whi, const u16* __restrict__ Wlo,
    const float* __restrict__ bcat, const float* __restrict__ lng,
    const float* __restrict__ lnb, int nrows) {
  __shared__ __align__(16) u16 sB[2][2][4096];  // [buf][hi/lo][8KB slice]
  int tid = threadIdx.x;
  int lane = tid & 63, wid = tid >> 6;
  long wt = (long)blockIdx.x * 4 + wid;
  long r0 = wt * 32;
  bool wvalid = (r0 < nrows);
  long r0c = wvalid ? r0 : 0;
  int rlo = lane & 15, khi = lane >> 4;
  u16* X16 = (u16*)X;

  uint4 h0, h1, l0, l1;
#define LOADB(KS) { \
    const uint4* sh_ = (const uint4*)(Whi + (size_t)(KS) * 4096); \
    const uint4* sl_ = (const uint4*)(Wlo + (size_t)(KS) * 4096); \
    h0 = sh_[tid]; h1 = sh_[256 + tid]; l0 = sl_[tid]; l1 = sl_[256 + tid]; }
#define WRITEB(BUF) { \
    ((uint4*)sB[BUF][0])[tid] = h0; ((uint4*)sB[BUF][0])[256 + tid] = h1; \
    ((uint4*)sB[BUF][1])[tid] = l0; ((uint4*)sB[BUF][1])[256 + tid] = l1; }

  LOADB(0);
  WRITEB(0);
  LOADB(1);

  // ---- A-frags: aggregate half (ag) + X half (xg), all in registers
  short8 ag[2][4], xg[2][4];
#pragma unroll
  for (int rs = 0; rs < 2; rs++) {
    long row = r0c + rs * 16 + rlo;
#pragma unroll
    for (int ks = 0; ks < 4; ks++)
      xg[rs][ks] = *(const short8*)(X16 + row * 128 + ks * 32 + khi * 8);
    if (GATHER == 0) {
#pragma unroll
      for (int ks = 0; ks < 4; ks++)
        ag[rs][ks] = *(const short8*)(AGG16 + row * 128 + ks * 32 + khi * 8);
    } else {
      int bgn = off[row], end = off[row + 1];
      float m[4][8];
#pragma unroll
      for (int ks = 0; ks < 4; ks++)
#pragma unroll
        for (int j = 0; j < 8; j++) m[ks][j] = 0.f;
      for (int t = bgn; t < end; t += 2) {
        int t1 = min(t + 1, end - 1);
        float w1 = (t + 1 < end) ? 1.f : 0.f;
        const u16* p0 = SRC16 + (size_t)csr[t] * 128 + khi * 8;
        const u16* p1 = SRC16 + (size_t)csr[t1] * 128 + khi * 8;
        uint4 va[4] = {*(const uint4*)(p0), *(const uint4*)(p0 + 32),
                       *(const uint4*)(p0 + 64), *(const uint4*)(p0 + 96)};
        uint4 vb[4] = {*(const uint4*)(p1), *(const uint4*)(p1 + 32),
                       *(const uint4*)(p1 + 64), *(const uint4*)(p1 + 96)};
#pragma unroll
        for (int ks = 0; ks < 4; ks++) {
          m[ks][0] += __uint_as_float((va[ks].x & 0xffffu) << 16) + w1 * __uint_as_float((vb[ks].x & 0xffffu) << 16);
          m[ks][1] += __uint_as_float((va[ks].x >> 16) << 16) + w1 * __uint_as_float((vb[ks].x >> 16) << 16);
          m[ks][2] += __uint_as_float((va[ks].y & 0xffffu) << 16) + w1 * __uint_as_float((vb[ks].y & 0xffffu) << 16);
          m[ks][3] += __uint_as_float((va[ks].y >> 16) << 16) + w1 * __uint_as_float((vb[ks].y >> 16) << 16);
          m[ks][4] += __uint_as_float((va[ks].z & 0xffffu) << 16) + w1 * __uint_as_float((vb[ks].z & 0xffffu) << 16);
          m[ks][5] += __uint_as_float((va[ks].z >> 16) << 16) + w1 * __uint_as_float((vb[ks].z >> 16) << 16);
          m[ks][6] += __uint_as_float((va[ks].w & 0xffffu) << 16) + w1 * __uint_as_float((vb[ks].w & 0xffffu) << 16);
          m[ks][7] += __uint_as_float((va[ks].w >> 16) << 16) + w1 * __uint_as_float((vb[ks].w >> 16) << 16);
        }
      }
      float inv = 1.f / fmaxf((float)(end - bgn), 1.f);
#pragma unroll
      for (int ks = 0; ks < 4; ks++) {
        short8 af;
#pragma unroll
        for (int j = 0; j < 8; j++) af[j] = (short)f2bf(m[ks][j] * inv);
        ag[rs][ks] = af;
      }
    }
  }

  __syncthreads();  // sB[0] ready

  // ---- MFMA main loop: K = 256 (8 ks), O = 128 (8 ot); B from LDS
  f32x4 acc[2][8];
#pragma unroll
  for (int rs = 0; rs < 2; rs++)
#pragma unroll
    for (int ot = 0; ot < 8; ot++) acc[rs][ot] = (f32x4){0.f, 0.f, 0.f, 0.f};

#pragma unroll
  for (int ks = 0; ks < 8; ks++) {
    const u16* sH = sB[ks & 1][0];
    const u16* sL = sB[ks & 1][1];
    short8 a0 = (ks < 4) ? ag[0][ks & 3] : xg[0][ks & 3];
    short8 a1 = (ks < 4) ? ag[1][ks & 3] : xg[1][ks & 3];
#pragma unroll
    for (int ot = 0; ot < 8; ot++) {
      short8 bh = *(const short8*)(sH + ot * 512 + lane * 8);
      short8 bl = *(const short8*)(sL + ot * 512 + lane * 8);
      acc[0][ot] = __builtin_amdgcn_mfma_f32_16x16x32_bf16(a0, bh, acc[0][ot], 0, 0, 0);
      acc[0][ot] = __builtin_amdgcn_mfma_f32_16x16x32_bf16(a0, bl, acc[0][ot], 0, 0, 0);
      acc[1][ot] = __builtin_amdgcn_mfma_f32_16x16x32_bf16(a1, bh, acc[1][ot], 0, 0, 0);
      acc[1][ot] = __builtin_amdgcn_mfma_f32_16x16x32_bf16(a1, bl, acc[1][ot], 0, 0, 0);
    }
    if (ks < 7) {
      WRITEB((ks + 1) & 1);
      if (ks < 6) LOADB(ks + 2);
      __syncthreads();
    }
  }
#undef LOADB
#undef WRITEB

  // ---- epilogue: bias -> silu -> LN (16-lane-group reduce) -> residual -> store
  if (!wvalid) return;  // no barriers below
  float bz[8], lg[8], lb[8];
#pragma unroll
  for (int ot = 0; ot < 8; ot++) {
    int c = ot * 16 + rlo;
    bz[ot] = bcat[c];
    lg[ot] = lng[c];
    lb[ot] = lnb[c];
  }
#pragma unroll
  for (int rs = 0; rs < 2; rs++) {
#pragma unroll
    for (int i = 0; i < 4; i++) {
      long row = r0 + rs * 16 + khi * 4 + i;
      float u[8], s1 = 0.f, s2 = 0.f;
#pragma unroll
      for (int ot = 0; ot < 8; ot++) {
        float z = acc[rs][ot][i] + bz[ot];
        float uu = silu_f(z);
        u[ot] = uu;
        s1 += uu;
        s2 += uu * uu;
      }
#pragma unroll
      for (int msk = 1; msk < 16; msk <<= 1) {
        s1 += __shfl_xor(s1, msk, 64);
        s2 += __shfl_xor(s2, msk, 64);
      }
      float mean = s1 * (1.f / 128.f);
      float var = s2 * (1.f / 128.f) - mean * mean;
      float rsq = rsqrtf(var + 1e-5f);
#pragma unroll
      for (int ot = 0; ot < 8; ot++) {
        size_t idx = (size_t)row * 128 + ot * 16 + rlo;
        float xr = bf16tof(X16[idx]);
        float o = (u[ot] - mean) * rsq * lg[ot] + lb[ot] + xr;
        X16[idx] = f2bf(o);
      }
    }
  }
}

// ---------------- batch stats / head ----------------

__global__ __launch_bounds__(256) void k_seg_counts(
    const int* __restrict__ batch, float* __restrict__ bcnt, int n) {
  int t = blockIdx.x * 256 + threadIdx.x;
  int r0 = t * 64;
  if (r0 >= n) return;
  int end = min(r0 + 64, n);
  int cur = batch[r0];
  float c = 0.f;
  for (int r = r0; r < end; r++) {
    int b = batch[r];
    if (b != cur) { atomicAdd(&bcnt[cur], c); cur = b; c = 0.f; }
    c += 1.f;
  }
  atomicAdd(&bcnt[cur], c);
}

__global__ __launch_bounds__(128) void k_bstats(
    const u32* __restrict__ X, const int* __restrict__ batch,
    float* __restrict__ bsum, float* __restrict__ bsq, int nrows) {
  __shared__ int sb[32];
  int r0 = blockIdx.x * 32;
  int c = threadIdx.x;
  if (c < 32) sb[c] = (r0 + c < nrows) ? batch[r0 + c] : -1;
  __syncthreads();
  float s = 0.f, q = 0.f;
  int cur = sb[0];
  const u16* Xh = (const u16*)X;
  for (int i = 0; i < 32; i++) {
    int r = r0 + i;
    if (r >= nrows) break;
    int b = sb[i];
    if (b != cur) {
      atomicAdd(&bsum[cur * H + c], s);
      atomicAdd(&bsq[cur * H + c], q);
      s = 0.f; q = 0.f; cur = b;
    }
    float v = bf16tof(Xh[(size_t)r * H + c]);
    s += v;
    q += v * v;
  }
  atomicAdd(&bsum[cur * H + c], s);
  atomicAdd(&bsq[cur * H + c], q);
}

__global__ __launch_bounds__(128) void k_head(
    const float* __restrict__ bsum_g, const float* __restrict__ bsq_g, const float* __restrict__ bcnt_g,
    const float* __restrict__ bsum_q, const float* __restrict__ bsq_q, const float* __restrict__ bcnt_q,
    const float* __restrict__ gf, const float* __restrict__ backend, const float* __restrict__ precision,
    const float* __restrict__ globW, const float* __restrict__ globb,
    const float* __restrict__ bbW, const float* __restrict__ bbb,
    const float* __restrict__ thrW, const float* __restrict__ thrb,
    const float* __restrict__ runW, const float* __restrict__ runb,
    float* __restrict__ out) {
  __shared__ float comb[5 * H + 2];
  __shared__ float feat[H];
  int b = blockIdx.x, c = threadIdx.x;
  float ig = 1.f / fmaxf(bcnt_g[b], 1.f);
  float iq = 1.f / fmaxf(bcnt_q[b], 1.f);
  float gm = bsum_g[b * H + c] * ig;
  float gs = sqrtf(fmaxf(bsq_g[b * H + c] * ig - gm * gm, 1e-6f));
  float qm = bsum_q[b * H + c] * iq;
  float qs = sqrtf(fmaxf(bsq_q[b * H + c] * iq - qm * qm, 1e-6f));
  float gl = globb[c];
#pragma unroll
  for (int j = 0; j < GDIM; j++) gl += gf[b * GDIM + j] * globW[j * H + c];
  gl = silu_f(gl);
  comb[c] = gm;
  comb[H + c] = gs;
  comb[2 * H + c] = qm;
  comb[3 * H + c] = qs;
  comb[4 * H + c] = gl;
  if (c == 0) {
    comb[5 * H] = backend[b];
    comb[5 * H + 1] = precision[b];
  }
  __syncthreads();
  float f = bbb[c];
  for (int k = 0; k < 5 * H + 2; k++) f += comb[k] * bbW[k * H + c];
  f = silu_f(f);
  feat[c] = f;
  __syncthreads();
  if (c < 10) {
    float o = thrb[c];
#pragma unroll
    for (int k = 0; k < H; k++) o += feat[k] * thrW[k * 10 + c];
    out[b * 10 + c] = o;
  }
  if (c == 64) {
    float o = runb[0];
    for (int k = 0; k < H; k++) o += feat[k] * runW[k];
    out[NB * 10 + b] = o;
  }
}

// ---------------- launch ----------------

extern "C" void kernel_launch(void* const* d_in, const int* in_sizes, int n_in,
                              void* d_out, int out_size, void* d_ws, size_t ws_size,
                              hipStream_t stream) {
  const int* gate_type = (const int*)d_in[0];
  const int* gate_arity = (const int*)d_in[1];
  const int* gate_dir = (const int*)d_in[2];
  const float* gate_ixn = (const float*)d_in[3];
  const float* qdeg = (const float*)d_in[4];
  const int* src_g2q = (const int*)d_in[5];
  const int* dst_g2q = (const int*)d_in[6];
  const int* src_q2g = (const int*)d_in[7];
  const int* dst_q2g = (const int*)d_in[8];
  const int* gate_batch = (const int*)d_in[9];
  const int* qubit_batch = (const int*)d_in[10];
  const float* gfeat = (const float*)d_in[11];
  const float* backend = (const float*)d_in[12];
  const float* precision = (const float*)d_in[13];
  const float* emb = (const float*)d_in[14];
  const float* gpW = (const float*)d_in[15];
  const float* gpb = (const float*)d_in[16];
  const float* qpW = (const float*)d_in[17];
  const float* qpb = (const float*)d_in[18];
  const float* g2q_ll_W = (const float*)d_in[19];
  const float* g2q_ll_b = (const float*)d_in[20];
  const float* g2q_lr_W = (const float*)d_in[21];
  const float* g2q_lr_b = (const float*)d_in[22];
  const float* q2g_ll_W = (const float*)d_in[23];
  const float* q2g_ll_b = (const float*)d_in[24];
  const float* q2g_lr_W = (const float*)d_in[25];
  const float* q2g_lr_b = (const float*)d_in[26];
  const float* gate_ln_g = (const float*)d_in[27];
  const float* gate_ln_b = (const float*)d_in[28];
  const float* qubit_ln_g = (const float*)d_in[29];
  const float* qubit_ln_b = (const float*)d_in[30];
  const float* globW = (const float*)d_in[31];
  const float* globb = (const float*)d_in[32];
  const float* bbW = (const float*)d_in[33];
  const float* bbb = (const float*)d_in[34];
  const float* thrW = (const float*)d_in[35];
  const float* thrb = (const float*)d_in[36];
  const float* runW = (const float*)d_in[37];
  const float* runb = (const float*)d_in[38];

  char* base = (char*)d_ws;
  u32* gx    = (u32*)base;                         // 128,000,000 B
  u32* qx    = gx + (size_t)NGATE * 64;            //  25,600,000 B
  u32* agg_q = qx + (size_t)NQUB * 64;             //  25,600,000 B
  u16* Whi   = (u16*)(agg_q + (size_t)NQUB * 64);  //     524,288 B
  u16* Wlo   = Whi + 8 * 32768;                    //     524,288 B
  float* bcat = (float*)(Wlo + 8 * 32768);         //       4,096 B
  int* offq = (int*)(bcat + 8 * 128);              // NQUB+1
  int* offg = offq + (NQUB + 1);                   // NGATE+1
  int* csrq = offg + (NGATE + 1);                  // NEDGE
  int* csrg = csrq + NEDGE;                        // NEDGE
  int* cntq = csrg + NEDGE;                        // NQUB
  int* cntg = cntq + NQUB;                         // NGATE
  int* bsumA = cntg + NGATE;                       // 512
  int* bsumB = bsumA + 512;                        // 512
  float* bsum_g = (float*)(bsumB + 512);
  float* bsq_g  = bsum_g + NB * H;
  float* bsum_q = bsq_g + NB * H;
  float* bsq_q  = bsum_q + NB * H;
  float* bcnt_g = bsq_q + NB * H;                  // NB
  float* bcnt_q = bcnt_g + NB;                     // NB
  size_t need = (size_t)((char*)(bcnt_q + NB) - base);
  if (ws_size < need) {
    k_sentinel<<<1, 1, 0, stream>>>((float*)d_out);
    return;
  }

  // ---- weight prep (layer-invariant) ----
  k_prep_w<<<(8 * 256 * 128 + 255) / 256, 256, 0, stream>>>(
      g2q_ll_W, g2q_lr_W, q2g_ll_W, q2g_lr_W, Whi, Wlo);
  k_prep_b<<<4, 256, 0, stream>>>(g2q_ll_b, g2q_lr_b, q2g_ll_b, q2g_lr_b, bcat);

  // ---- CSR build (layer-invariant) ----
  hipMemsetAsync(cntq, 0, (size_t)(NQUB + NGATE) * sizeof(int), stream);
  k_count<<<(NEDGE + 255) / 256, 256, 0, stream>>>(dst_g2q, dst_q2g, cntq, cntg);
  const int nbq = (NQUB + 1023) / 1024, nbg = (NGATE + 1023) / 1024;
  k_scan_chunk<<<nbq, 1024, 0, stream>>>(cntq, NQUB, offq + 1, bsumA);
  k_scan_chunk<<<1, 1024, 0, stream>>>(bsumA, nbq, bsumB, nullptr);
  k_scan_add<<<nbq, 1024, 0, stream>>>(NQUB, offq, bsumB);
  k_scan_chunk<<<nbg, 1024, 0, stream>>>(cntg, NGATE, offg + 1, bsumA);
  k_scan_chunk<<<1, 1024, 0, stream>>>(bsumA, nbg, bsumB, nullptr);
  k_scan_add<<<nbg, 1024, 0, stream>>>(NGATE, offg, bsumB);
  hipMemsetAsync(cntq, 0, (size_t)(NQUB + NGATE) * sizeof(int), stream);
  k_csr_fill<<<(NEDGE + 255) / 256, 256, 0, stream>>>(
      src_g2q, dst_g2q, src_q2g, dst_q2g, offq, offg, cntq, cntg, csrq, csrg);

  // ---- batch seg counts + stats init ----
  size_t stats_floats = 4ULL * NB * H + 2ULL * NB;
  hipMemsetAsync(bsum_g, 0, stats_floats * sizeof(float), stream);
  k_seg_counts<<<(NGATE / 64 + 256) / 256, 256, 0, stream>>>(gate_batch, bcnt_g, NGATE);
  k_seg_counts<<<(NQUB / 64 + 256) / 256, 256, 0, stream>>>(qubit_batch, bcnt_q, NQUB);

  // ---- projections ----
  k_gate_proj<<<1024, 256, 0, stream>>>(gate_type, gate_arity, gate_dir, gate_ixn,
                                        emb, gpW, gpb, gx);
  k_qubit_proj<<<(NQUB * 64 + 255) / 256, 256, 0, stream>>>(qdeg, qpW, qpb, qx);

  // ---- layers ----
  const int blocks_g = (NGATE + 127) / 128;  // 3907
  const int blocks_q = (NQUB + 127) / 128;   // 782
  for (int l = 0; l < NL; l++) {
    const u16* WhiG = Whi + (size_t)(l * 2 + 1) * 32768;
    const u16* WloG = Wlo + (size_t)(l * 2 + 1) * 32768;
    const float* bcG = bcat + (l * 2 + 1) * 128;
    const u16* WhiQ = Whi + (size_t)(l * 2) * 32768;
    const u16* WloQ = Wlo + (size_t)(l * 2) * 32768;
    const float* bcQ = bcat + (l * 2) * 128;
    // agg_q = seg-mean(old gx)   [before gate-side overwrites gx]
    k_gather_rows<<<(NQUB + 3) / 4, 256, 0, stream>>>(gx, offq, csrq, agg_q, NQUB);
    // gate side (fused gather of old qx): gx = LN(silu([mean(qx[nbr]) | gx]@W + b)) + gx
    k_layer<1><<<blocks_g, 256, 0, stream>>>(
        nullptr, (const u16*)qx, offg, csrg, gx,
        WhiG, WloG, bcG, gate_ln_g + (size_t)l * H, gate_ln_b + (size_t)l * H, NGATE);
    // qubit side: qx = LN(silu([agg_q | qx]@W + b)) + qx
    k_layer<0><<<blocks_q, 256, 0, stream>>>(
        (const u16*)agg_q, nullptr, nullptr, nullptr, qx,
        WhiQ, WloQ, bcQ, qubit_ln_g + (size_t)l * H, qubit_ln_b + (size_t)l * H, NQUB);
  }

  // ---- readout ----
  k_bstats<<<NGATE / 32, 128, 0, stream>>>(gx, gate_batch, bsum_g, bsq_g, NGATE);
  k_bstats<<<NQUB / 32, 128, 0, stream>>>(qx, qubit_batch, bsum_q, bsq_q, NQUB);
  k_head<<<NB, 128, 0, stream>>>(bsum_g, bsq_g, bcnt_g, bsum_q, bsq_q, bcnt_q,
                                 gfeat, backend, precision, globW, globb,
                                 bbW, bbb, thrW, thrb, runW, runb, (float*)d_out);
}